// Round 1
// baseline (1400.887 us; speedup 1.0000x reference)
//
#include <hip/hip_runtime.h>

#define V_IN 128
#define U_IN 64
#define HID 128
#define K1  (V_IN + HID + U_IN)   // 320

// ---------------- scatter: agg[col[e]] += edge_attr[e] ----------------
// 32 lanes per edge, each lane handles 4 consecutive floats (float4 load).
__global__ __launch_bounds__(256) void scatter_kernel(
    const int* __restrict__ edge_index,   // [2, E] (harness delivers integer as int32)
    const float* __restrict__ edge_attr,  // [E, HID]
    float* __restrict__ agg,              // [N, HID]
    int E)
{
    int tid  = blockIdx.x * 256 + threadIdx.x;
    int e    = tid >> 5;        // 32 lanes per edge
    int lane = tid & 31;
    if (e >= E) return;
    int col = edge_index[E + e];                       // row 1 of edge_index
    float4 v = ((const float4*)(edge_attr + (size_t)e * HID))[lane];
    float* dst = agg + (size_t)col * HID + lane * 4;
    atomicAdd(dst + 0, v.x);
    atomicAdd(dst + 1, v.y);
    atomicAdd(dst + 2, v.z);
    atomicAdd(dst + 3, v.w);
}

// ---------------- fused 2-layer MLP ----------------
// block = 256 threads (8 ty x 32 tx), TILE_N = 32 nodes per block.
// A tile: [32][320] concat(x, agg, u[batch]) staged in LDS, pitch 321
// (321 % 32 == 1 -> bank = (row + k) % 32, conflict-free across ty rows).
// Each thread computes a 4x4 micro-tile (4 nodes x 4 output cols).
#define TILE_N 32
#define LDA 321
#define LDH 129

__global__ __launch_bounds__(256) void mlp_kernel(
    const float* __restrict__ x,
    const float* __restrict__ agg,
    const float* __restrict__ u,
    const int*   __restrict__ batch,
    const float* __restrict__ W1, const float* __restrict__ b1,
    const float* __restrict__ W2, const float* __restrict__ b2,
    float* __restrict__ out, int N)
{
    __shared__ float A[TILE_N * LDA];
    __shared__ float H[TILE_N * LDH];
    const int tid = threadIdx.x;
    const int n0  = blockIdx.x * TILE_N;

    // ---- stage concat input: 80 float4 segments per row (32 x, 32 agg, 16 u)
    #pragma unroll
    for (int it = 0; it < (TILE_N * 80) / 256; ++it) {   // 10 iters
        int idx = tid + it * 256;
        int row = idx / 80;
        int seg = idx - row * 80;
        int n   = n0 + row;
        float4 v = make_float4(0.f, 0.f, 0.f, 0.f);
        if (n < N) {
            if (seg < 32) {
                v = ((const float4*)(x + (size_t)n * V_IN))[seg];
            } else if (seg < 64) {
                v = ((const float4*)(agg + (size_t)n * HID))[seg - 32];
            } else {
                int b = batch[n];
                v = ((const float4*)(u + (size_t)b * U_IN))[seg - 64];
            }
        }
        float* dst = &A[row * LDA + seg * 4];
        dst[0] = v.x; dst[1] = v.y; dst[2] = v.z; dst[3] = v.w;
    }
    __syncthreads();

    const int tx = tid & 31;   // output-col group: cols [4*tx, 4*tx+3]
    const int ty = tid >> 5;   // node group: rows [4*ty, 4*ty+3]

    // ---- layer 1: [32x320] @ [320x128] + b1, relu
    float acc[4][4];
    {
        float4 bv = ((const float4*)b1)[tx];
        #pragma unroll
        for (int i = 0; i < 4; ++i) {
            acc[i][0] = bv.x; acc[i][1] = bv.y; acc[i][2] = bv.z; acc[i][3] = bv.w;
        }
    }
    #pragma unroll 4
    for (int k = 0; k < K1; ++k) {
        float4 w = ((const float4*)(W1 + (size_t)k * HID))[tx];
        #pragma unroll
        for (int i = 0; i < 4; ++i) {
            float a = A[(ty * 4 + i) * LDA + k];
            acc[i][0] = fmaf(a, w.x, acc[i][0]);
            acc[i][1] = fmaf(a, w.y, acc[i][1]);
            acc[i][2] = fmaf(a, w.z, acc[i][2]);
            acc[i][3] = fmaf(a, w.w, acc[i][3]);
        }
    }
    #pragma unroll
    for (int i = 0; i < 4; ++i)
        #pragma unroll
        for (int j = 0; j < 4; ++j)
            H[(ty * 4 + i) * LDH + tx * 4 + j] = fmaxf(acc[i][j], 0.f);
    __syncthreads();

    // ---- layer 2: [32x128] @ [128x128] + b2
    float acc2[4][4];
    {
        float4 bv = ((const float4*)b2)[tx];
        #pragma unroll
        for (int i = 0; i < 4; ++i) {
            acc2[i][0] = bv.x; acc2[i][1] = bv.y; acc2[i][2] = bv.z; acc2[i][3] = bv.w;
        }
    }
    #pragma unroll 4
    for (int k = 0; k < HID; ++k) {
        float4 w = ((const float4*)(W2 + (size_t)k * HID))[tx];
        #pragma unroll
        for (int i = 0; i < 4; ++i) {
            float a = H[(ty * 4 + i) * LDH + k];
            acc2[i][0] = fmaf(a, w.x, acc2[i][0]);
            acc2[i][1] = fmaf(a, w.y, acc2[i][1]);
            acc2[i][2] = fmaf(a, w.z, acc2[i][2]);
            acc2[i][3] = fmaf(a, w.w, acc2[i][3]);
        }
    }

    // ---- store
    #pragma unroll
    for (int i = 0; i < 4; ++i) {
        int n = n0 + ty * 4 + i;
        if (n < N) {
            float4 o = make_float4(acc2[i][0], acc2[i][1], acc2[i][2], acc2[i][3]);
            ((float4*)(out + (size_t)n * HID))[tx] = o;
        }
    }
}

extern "C" void kernel_launch(void* const* d_in, const int* in_sizes, int n_in,
                              void* d_out, int out_size, void* d_ws, size_t ws_size,
                              hipStream_t stream) {
    const float* x          = (const float*)d_in[0];
    const int*   edge_index = (const int*)  d_in[1];
    const float* edge_attr  = (const float*)d_in[2];
    const float* u          = (const float*)d_in[3];
    const int*   batch      = (const int*)  d_in[4];
    const float* W1         = (const float*)d_in[5];
    const float* b1         = (const float*)d_in[6];
    const float* W2         = (const float*)d_in[7];
    const float* b2         = (const float*)d_in[8];
    float* out = (float*)d_out;

    const int N = in_sizes[0] / V_IN;
    const int E = in_sizes[1] / 2;

    float* agg = (float*)d_ws;   // [N, HID]

    // zero the aggregation buffer (capture-safe)
    hipMemsetAsync(agg, 0, (size_t)N * HID * sizeof(float), stream);

    // scatter-add edge_attr into destination nodes
    {
        int threads_total = E * 32;
        int grid = (threads_total + 255) / 256;
        scatter_kernel<<<grid, 256, 0, stream>>>(edge_index, edge_attr, agg, E);
    }

    // fused MLP
    {
        int grid = (N + TILE_N - 1) / TILE_N;
        mlp_kernel<<<grid, 256, 0, stream>>>(x, agg, u, batch, W1, b1, W2, b2, out, N);
    }
}

// Round 2
// 506.352 us; speedup vs baseline: 2.7666x; 2.7666x over previous
//
#include <hip/hip_runtime.h>

#define V_IN 128
#define U_IN 64
#define HID 128
#define K1  (V_IN + HID + U_IN)   // 320
#define TILE_N 32
#define LDA 321
#define LDH 129

// ---------- CSR build ----------

__global__ __launch_bounds__(256) void hist_kernel(
    const int* __restrict__ col, int* __restrict__ deg, int E)
{
    int e = blockIdx.x * 256 + threadIdx.x;
    if (e < E) atomicAdd(&deg[col[e]], 1);
}

// partial sums: each block covers 1024 elements of deg
__global__ __launch_bounds__(256) void scan_partial(
    const int* __restrict__ deg, int* __restrict__ blockSums, int N)
{
    __shared__ int sdata[256];
    int base = blockIdx.x * 1024;
    int tid  = threadIdx.x;
    int s = 0;
    #pragma unroll
    for (int j = 0; j < 4; ++j) {
        int i = base + tid * 4 + j;
        if (i < N) s += deg[i];
    }
    sdata[tid] = s;
    __syncthreads();
    for (int off = 128; off > 0; off >>= 1) {
        if (tid < off) sdata[tid] += sdata[tid + off];
        __syncthreads();
    }
    if (tid == 0) blockSums[blockIdx.x] = sdata[0];
}

// exclusive scan of blockSums (NB <= 1024), single block
__global__ __launch_bounds__(1024) void scan_blocksums(
    int* __restrict__ blockSums, int NB)
{
    __shared__ int s[1024];
    int tid = threadIdx.x;
    int v = (tid < NB) ? blockSums[tid] : 0;
    s[tid] = v;
    __syncthreads();
    for (int off = 1; off < 1024; off <<= 1) {
        int t = (tid >= off) ? s[tid - off] : 0;
        __syncthreads();
        s[tid] += t;
        __syncthreads();
    }
    if (tid < NB) blockSums[tid] = s[tid] - v;   // exclusive
}

// final: offsets[i] = exclusive scan of deg; cur[i] = offsets[i]
__global__ __launch_bounds__(256) void scan_final(
    const int* __restrict__ deg, const int* __restrict__ blockSums,
    int* __restrict__ offsets, int* __restrict__ cur, int N, int E)
{
    __shared__ int sdata[256];
    int base = blockIdx.x * 1024;
    int tid  = threadIdx.x;
    int loc[4];
    int s = 0;
    #pragma unroll
    for (int j = 0; j < 4; ++j) {
        int i = base + tid * 4 + j;
        loc[j] = (i < N) ? deg[i] : 0;
        s += loc[j];
    }
    int mine = s;
    sdata[tid] = s;
    __syncthreads();
    for (int off = 1; off < 256; off <<= 1) {
        int t = (tid >= off) ? sdata[tid - off] : 0;
        __syncthreads();
        sdata[tid] += t;
        __syncthreads();
    }
    int prefix = blockSums[blockIdx.x] + sdata[tid] - mine;
    #pragma unroll
    for (int j = 0; j < 4; ++j) {
        int i = base + tid * 4 + j;
        if (i < N) { offsets[i] = prefix; cur[i] = prefix; prefix += loc[j]; }
    }
    if (blockIdx.x == 0 && tid == 0) offsets[N] = E;
}

__global__ __launch_bounds__(256) void fill_kernel(
    const int* __restrict__ col, int* __restrict__ cur,
    int* __restrict__ eidx, int E)
{
    int e = blockIdx.x * 256 + threadIdx.x;
    if (e < E) {
        int p = atomicAdd(&cur[col[e]], 1);
        eidx[p] = e;
    }
}

// ---------- fused gather + 2-layer MLP ----------
// block = 256 threads (8 half-waves x 32 lanes), TILE_N = 32 nodes.
// Gather phase: half-wave hw sums edge_attr rows for nodes hw*4..hw*4+3
// directly into the agg section of the A tile (no HBM round-trip).
__global__ __launch_bounds__(256) void mlp_kernel(
    const float* __restrict__ x,
    const float* __restrict__ edge_attr,
    const int*   __restrict__ offsets,
    const int*   __restrict__ eidx,
    const float* __restrict__ u,
    const int*   __restrict__ batch,
    const float* __restrict__ W1, const float* __restrict__ b1,
    const float* __restrict__ W2, const float* __restrict__ b2,
    float* __restrict__ out, int N)
{
    __shared__ float A[TILE_N * LDA];
    __shared__ float H[TILE_N * LDH];
    const int tid = threadIdx.x;
    const int n0  = blockIdx.x * TILE_N;

    // ---- stage x (segs 0..31 -> cols 0..127) and u (segs 32..47 -> cols 256..319)
    #pragma unroll
    for (int it = 0; it < (TILE_N * 48) / 256; ++it) {   // 6 iters
        int idx = tid + it * 256;
        int row = idx / 48;
        int seg = idx - row * 48;
        int n   = n0 + row;
        float4 v = make_float4(0.f, 0.f, 0.f, 0.f);
        int colbase;
        if (seg < 32) {
            if (n < N) v = ((const float4*)(x + (size_t)n * V_IN))[seg];
            colbase = seg * 4;
        } else {
            if (n < N) {
                int b = batch[n];
                v = ((const float4*)(u + (size_t)b * U_IN))[seg - 32];
            }
            colbase = V_IN + HID + (seg - 32) * 4;
        }
        float* dst = &A[row * LDA + colbase];
        dst[0] = v.x; dst[1] = v.y; dst[2] = v.z; dst[3] = v.w;
    }

    // ---- gather: agg section (cols 128..255)
    {
        const int hw   = tid >> 5;   // half-wave 0..7
        const int lane = tid & 31;
        #pragma unroll
        for (int i = 0; i < 4; ++i) {
            int r = hw * 4 + i;
            int n = n0 + r;
            float4 acc = make_float4(0.f, 0.f, 0.f, 0.f);
            if (n < N) {
                int s = offsets[n];
                int t = offsets[n + 1];
                int p = s;
                int e_next = (p < t) ? eidx[p] : 0;
                while (p < t) {
                    int e = e_next;
                    ++p;
                    if (p < t) e_next = eidx[p];
                    float4 v = ((const float4*)(edge_attr + (size_t)e * HID))[lane];
                    acc.x += v.x; acc.y += v.y; acc.z += v.z; acc.w += v.w;
                }
            }
            float* dst = &A[r * LDA + V_IN + lane * 4];
            dst[0] = acc.x; dst[1] = acc.y; dst[2] = acc.z; dst[3] = acc.w;
        }
    }
    __syncthreads();

    const int tx = tid & 31;   // output-col group: cols [4*tx, 4*tx+3]
    const int ty = tid >> 5;   // node group: rows [4*ty, 4*ty+3]

    // ---- layer 1: [32x320] @ [320x128] + b1, relu
    float acc[4][4];
    {
        float4 bv = ((const float4*)b1)[tx];
        #pragma unroll
        for (int i = 0; i < 4; ++i) {
            acc[i][0] = bv.x; acc[i][1] = bv.y; acc[i][2] = bv.z; acc[i][3] = bv.w;
        }
    }
    #pragma unroll 4
    for (int k = 0; k < K1; ++k) {
        float4 w = ((const float4*)(W1 + (size_t)k * HID))[tx];
        #pragma unroll
        for (int i = 0; i < 4; ++i) {
            float a = A[(ty * 4 + i) * LDA + k];
            acc[i][0] = fmaf(a, w.x, acc[i][0]);
            acc[i][1] = fmaf(a, w.y, acc[i][1]);
            acc[i][2] = fmaf(a, w.z, acc[i][2]);
            acc[i][3] = fmaf(a, w.w, acc[i][3]);
        }
    }
    #pragma unroll
    for (int i = 0; i < 4; ++i)
        #pragma unroll
        for (int j = 0; j < 4; ++j)
            H[(ty * 4 + i) * LDH + tx * 4 + j] = fmaxf(acc[i][j], 0.f);
    __syncthreads();

    // ---- layer 2: [32x128] @ [128x128] + b2
    float acc2[4][4];
    {
        float4 bv = ((const float4*)b2)[tx];
        #pragma unroll
        for (int i = 0; i < 4; ++i) {
            acc2[i][0] = bv.x; acc2[i][1] = bv.y; acc2[i][2] = bv.z; acc2[i][3] = bv.w;
        }
    }
    #pragma unroll 4
    for (int k = 0; k < HID; ++k) {
        float4 w = ((const float4*)(W2 + (size_t)k * HID))[tx];
        #pragma unroll
        for (int i = 0; i < 4; ++i) {
            float a = H[(ty * 4 + i) * LDH + k];
            acc2[i][0] = fmaf(a, w.x, acc2[i][0]);
            acc2[i][1] = fmaf(a, w.y, acc2[i][1]);
            acc2[i][2] = fmaf(a, w.z, acc2[i][2]);
            acc2[i][3] = fmaf(a, w.w, acc2[i][3]);
        }
    }

    // ---- store
    #pragma unroll
    for (int i = 0; i < 4; ++i) {
        int n = n0 + ty * 4 + i;
        if (n < N) {
            float4 o = make_float4(acc2[i][0], acc2[i][1], acc2[i][2], acc2[i][3]);
            ((float4*)(out + (size_t)n * HID))[tx] = o;
        }
    }
}

extern "C" void kernel_launch(void* const* d_in, const int* in_sizes, int n_in,
                              void* d_out, int out_size, void* d_ws, size_t ws_size,
                              hipStream_t stream) {
    const float* x          = (const float*)d_in[0];
    const int*   edge_index = (const int*)  d_in[1];
    const float* edge_attr  = (const float*)d_in[2];
    const float* u          = (const float*)d_in[3];
    const int*   batch      = (const int*)  d_in[4];
    const float* W1         = (const float*)d_in[5];
    const float* b1         = (const float*)d_in[6];
    const float* W2         = (const float*)d_in[7];
    const float* b2         = (const float*)d_in[8];
    float* out = (float*)d_out;

    const int N = in_sizes[0] / V_IN;
    const int E = in_sizes[1] / 2;
    const int* col = edge_index + E;   // row 1 = destination

    // ws layout (ints)
    int* deg       = (int*)d_ws;            // N
    int* cur       = deg + N;               // N
    int* offsets   = cur + N;               // N+1
    int* blockSums = offsets + N + 1;       // up to 1024, padded to 2048
    int* eidx      = blockSums + 2048;      // E

    const int NB = (N + 1023) / 1024;

    hipMemsetAsync(deg, 0, (size_t)N * sizeof(int), stream);

    hist_kernel   <<<(E + 255) / 256, 256, 0, stream>>>(col, deg, E);
    scan_partial  <<<NB, 256, 0, stream>>>(deg, blockSums, N);
    scan_blocksums<<<1, 1024, 0, stream>>>(blockSums, NB);
    scan_final    <<<NB, 256, 0, stream>>>(deg, blockSums, offsets, cur, N, E);
    fill_kernel   <<<(E + 255) / 256, 256, 0, stream>>>(col, cur, eidx, E);

    mlp_kernel<<<(N + TILE_N - 1) / TILE_N, 256, 0, stream>>>(
        x, edge_attr, offsets, eidx, u, batch, W1, b1, W2, b2, out, N);
}

// Round 3
// 435.716 us; speedup vs baseline: 3.2151x; 1.1621x over previous
//
#include <hip/hip_runtime.h>

#define V_IN 128
#define U_IN 64
#define HID 128
#define K1  (V_IN + HID + U_IN)   // 320
#define TILE_N 32
#define LDA 321
#define LDH 129

// ---------- CSR build ----------

__global__ __launch_bounds__(256) void hist_kernel(
    const int* __restrict__ col, int* __restrict__ deg, int E)
{
    int e = blockIdx.x * 256 + threadIdx.x;
    if (e < E) atomicAdd(&deg[col[e]], 1);
}

__global__ __launch_bounds__(256) void scan_partial(
    const int* __restrict__ deg, int* __restrict__ blockSums, int N)
{
    __shared__ int sdata[256];
    int base = blockIdx.x * 1024;
    int tid  = threadIdx.x;
    int s = 0;
    #pragma unroll
    for (int j = 0; j < 4; ++j) {
        int i = base + tid * 4 + j;
        if (i < N) s += deg[i];
    }
    sdata[tid] = s;
    __syncthreads();
    for (int off = 128; off > 0; off >>= 1) {
        if (tid < off) sdata[tid] += sdata[tid + off];
        __syncthreads();
    }
    if (tid == 0) blockSums[blockIdx.x] = sdata[0];
}

__global__ __launch_bounds__(1024) void scan_blocksums(
    int* __restrict__ blockSums, int NB)
{
    __shared__ int s[1024];
    int tid = threadIdx.x;
    int v = (tid < NB) ? blockSums[tid] : 0;
    s[tid] = v;
    __syncthreads();
    for (int off = 1; off < 1024; off <<= 1) {
        int t = (tid >= off) ? s[tid - off] : 0;
        __syncthreads();
        s[tid] += t;
        __syncthreads();
    }
    if (tid < NB) blockSums[tid] = s[tid] - v;   // exclusive
}

__global__ __launch_bounds__(256) void scan_final(
    const int* __restrict__ deg, const int* __restrict__ blockSums,
    int* __restrict__ offsets, int* __restrict__ cur, int N, int E)
{
    __shared__ int sdata[256];
    int base = blockIdx.x * 1024;
    int tid  = threadIdx.x;
    int loc[4];
    int s = 0;
    #pragma unroll
    for (int j = 0; j < 4; ++j) {
        int i = base + tid * 4 + j;
        loc[j] = (i < N) ? deg[i] : 0;
        s += loc[j];
    }
    int mine = s;
    sdata[tid] = s;
    __syncthreads();
    for (int off = 1; off < 256; off <<= 1) {
        int t = (tid >= off) ? sdata[tid - off] : 0;
        __syncthreads();
        sdata[tid] += t;
        __syncthreads();
    }
    int prefix = blockSums[blockIdx.x] + sdata[tid] - mine;
    #pragma unroll
    for (int j = 0; j < 4; ++j) {
        int i = base + tid * 4 + j;
        if (i < N) { offsets[i] = prefix; cur[i] = prefix; prefix += loc[j]; }
    }
    if (blockIdx.x == 0 && tid == 0) offsets[N] = E;
}

__global__ __launch_bounds__(256) void fill_kernel(
    const int* __restrict__ col, int* __restrict__ cur,
    int* __restrict__ eidx, int E)
{
    int e = blockIdx.x * 256 + threadIdx.x;
    if (e < E) {
        int p = atomicAdd(&cur[col[e]], 1);
        eidx[p] = e;
    }
}

// ---------- gather: agg[n] = sum of edge_attr rows (CSR), massively parallel ----------
// one thread per (node, float4-column): 3.2M threads -> full occupancy, latency hidden by TLP
__global__ __launch_bounds__(256) void gather_kernel(
    const float* __restrict__ edge_attr,
    const int*   __restrict__ offsets,
    const int*   __restrict__ eidx,
    float* __restrict__ agg, int N)
{
    int gid = blockIdx.x * 256 + threadIdx.x;
    int n = gid >> 5;
    int c = gid & 31;
    if (n >= N) return;
    int s = offsets[n];
    int t = offsets[n + 1];
    float4 acc = make_float4(0.f, 0.f, 0.f, 0.f);
    int p  = s;
    int e0 = (p < t) ? eidx[p] : 0;
    while (p < t) {
        int e1 = (p + 1 < t) ? eidx[p + 1] : 0;     // prefetch next index
        float4 v = ((const float4*)(edge_attr + (size_t)e0 * HID))[c];
        acc.x += v.x; acc.y += v.y; acc.z += v.z; acc.w += v.w;
        e0 = e1;
        ++p;
    }
    ((float4*)(agg + (size_t)n * HID))[c] = acc;
}

// ---------- 2-layer MLP, LDS-lean (H overlays A) ----------
__global__ __launch_bounds__(256) void mlp_kernel(
    const float* __restrict__ x,
    const float* __restrict__ agg,
    const float* __restrict__ u,
    const int*   __restrict__ batch,
    const float* __restrict__ W1, const float* __restrict__ b1,
    const float* __restrict__ W2, const float* __restrict__ b2,
    float* __restrict__ out, int N)
{
    __shared__ float A[TILE_N * LDA];   // 41 KB; H tile overlays this after layer 1
    const int tid = threadIdx.x;
    const int n0  = blockIdx.x * TILE_N;

    // ---- stage concat input: 80 float4 segments per row (32 x, 32 agg, 16 u)
    #pragma unroll
    for (int it = 0; it < (TILE_N * 80) / 256; ++it) {   // 10 iters
        int idx = tid + it * 256;
        int row = idx / 80;
        int seg = idx - row * 80;
        int n   = n0 + row;
        float4 v = make_float4(0.f, 0.f, 0.f, 0.f);
        if (n < N) {
            if (seg < 32) {
                v = ((const float4*)(x + (size_t)n * V_IN))[seg];
            } else if (seg < 64) {
                v = ((const float4*)(agg + (size_t)n * HID))[seg - 32];
            } else {
                int b = batch[n];
                v = ((const float4*)(u + (size_t)b * U_IN))[seg - 64];
            }
        }
        float* dst = &A[row * LDA + seg * 4];
        dst[0] = v.x; dst[1] = v.y; dst[2] = v.z; dst[3] = v.w;
    }
    __syncthreads();

    const int tx = tid & 31;   // output-col group: cols [4*tx, 4*tx+3]
    const int ty = tid >> 5;   // node group: rows [4*ty, 4*ty+3]

    // ---- layer 1: [32x320] @ [320x128] + b1, relu
    float acc[4][4];
    {
        float4 bv = ((const float4*)b1)[tx];
        #pragma unroll
        for (int i = 0; i < 4; ++i) {
            acc[i][0] = bv.x; acc[i][1] = bv.y; acc[i][2] = bv.z; acc[i][3] = bv.w;
        }
    }
    #pragma unroll 4
    for (int k = 0; k < K1; ++k) {
        float4 w = ((const float4*)(W1 + (size_t)k * HID))[tx];
        #pragma unroll
        for (int i = 0; i < 4; ++i) {
            float a = A[(ty * 4 + i) * LDA + k];
            acc[i][0] = fmaf(a, w.x, acc[i][0]);
            acc[i][1] = fmaf(a, w.y, acc[i][1]);
            acc[i][2] = fmaf(a, w.z, acc[i][2]);
            acc[i][3] = fmaf(a, w.w, acc[i][3]);
        }
    }
    __syncthreads();   // all layer-1 reads of A done; safe to overlay H

    #pragma unroll
    for (int i = 0; i < 4; ++i)
        #pragma unroll
        for (int j = 0; j < 4; ++j)
            A[(ty * 4 + i) * LDH + tx * 4 + j] = fmaxf(acc[i][j], 0.f);
    __syncthreads();

    // ---- layer 2: [32x128] @ [128x128] + b2
    float acc2[4][4];
    {
        float4 bv = ((const float4*)b2)[tx];
        #pragma unroll
        for (int i = 0; i < 4; ++i) {
            acc2[i][0] = bv.x; acc2[i][1] = bv.y; acc2[i][2] = bv.z; acc2[i][3] = bv.w;
        }
    }
    #pragma unroll 4
    for (int k = 0; k < HID; ++k) {
        float4 w = ((const float4*)(W2 + (size_t)k * HID))[tx];
        #pragma unroll
        for (int i = 0; i < 4; ++i) {
            float a = A[(ty * 4 + i) * LDH + k];
            acc2[i][0] = fmaf(a, w.x, acc2[i][0]);
            acc2[i][1] = fmaf(a, w.y, acc2[i][1]);
            acc2[i][2] = fmaf(a, w.z, acc2[i][2]);
            acc2[i][3] = fmaf(a, w.w, acc2[i][3]);
        }
    }

    // ---- store
    #pragma unroll
    for (int i = 0; i < 4; ++i) {
        int n = n0 + ty * 4 + i;
        if (n < N) {
            float4 o = make_float4(acc2[i][0], acc2[i][1], acc2[i][2], acc2[i][3]);
            ((float4*)(out + (size_t)n * HID))[tx] = o;
        }
    }
}

extern "C" void kernel_launch(void* const* d_in, const int* in_sizes, int n_in,
                              void* d_out, int out_size, void* d_ws, size_t ws_size,
                              hipStream_t stream) {
    const float* x          = (const float*)d_in[0];
    const int*   edge_index = (const int*)  d_in[1];
    const float* edge_attr  = (const float*)d_in[2];
    const float* u          = (const float*)d_in[3];
    const int*   batch      = (const int*)  d_in[4];
    const float* W1         = (const float*)d_in[5];
    const float* b1         = (const float*)d_in[6];
    const float* W2         = (const float*)d_in[7];
    const float* b2         = (const float*)d_in[8];
    float* out = (float*)d_out;

    const int N = in_sizes[0] / V_IN;
    const int E = in_sizes[1] / 2;
    const int* col = edge_index + E;   // row 1 = destination

    // ws layout
    float* agg     = (float*)d_ws;           // N*HID floats (51.2 MB)
    int* deg       = (int*)(agg + (size_t)N * HID);  // N
    int* cur       = deg + N;                // N
    int* offsets   = cur + N;                // N+1
    int* blockSums = offsets + N + 1;        // padded 2048
    int* eidx      = blockSums + 2048;       // E

    const int NB = (N + 1023) / 1024;

    hipMemsetAsync(deg, 0, (size_t)N * sizeof(int), stream);

    hist_kernel   <<<(E + 255) / 256, 256, 0, stream>>>(col, deg, E);
    scan_partial  <<<NB, 256, 0, stream>>>(deg, blockSums, N);
    scan_blocksums<<<1, 1024, 0, stream>>>(blockSums, NB);
    scan_final    <<<NB, 256, 0, stream>>>(deg, blockSums, offsets, cur, N, E);
    fill_kernel   <<<(E + 255) / 256, 256, 0, stream>>>(col, cur, eidx, E);

    gather_kernel <<<((size_t)N * 32 + 255) / 256, 256, 0, stream>>>(
        edge_attr, offsets, eidx, agg, N);

    mlp_kernel<<<(N + TILE_N - 1) / TILE_N, 256, 0, stream>>>(
        x, agg, u, batch, W1, b1, W2, b2, out, N);
}

// Round 5
// 287.313 us; speedup vs baseline: 4.8758x; 1.5165x over previous
//
#include <hip/hip_runtime.h>

#define V_IN 128
#define U_IN 64
#define HID 128
#define K1  (V_IN + HID + U_IN)   // 320

typedef __attribute__((ext_vector_type(8))) short bf16x8;
typedef __attribute__((ext_vector_type(4))) float f32x4;

static __device__ __forceinline__ unsigned short f2bf(float f) {
    union { float f; unsigned u; } v; v.f = f;
    unsigned r = v.u + 0x7FFFu + ((v.u >> 16) & 1u);   // RNE
    return (unsigned short)(r >> 16);
}

// ---------- CSR build ----------

__global__ __launch_bounds__(256) void hist_kernel(
    const int* __restrict__ col, int* __restrict__ deg, int E)
{
    int e = blockIdx.x * 256 + threadIdx.x;
    if (e < E) atomicAdd(&deg[col[e]], 1);
}

__global__ __launch_bounds__(256) void scan_partial(
    const int* __restrict__ deg, int* __restrict__ blockSums, int N)
{
    __shared__ int sdata[256];
    int base = blockIdx.x * 1024;
    int tid  = threadIdx.x;
    int s = 0;
    #pragma unroll
    for (int j = 0; j < 4; ++j) {
        int i = base + tid * 4 + j;
        if (i < N) s += deg[i];
    }
    sdata[tid] = s;
    __syncthreads();
    for (int off = 128; off > 0; off >>= 1) {
        if (tid < off) sdata[tid] += sdata[tid + off];
        __syncthreads();
    }
    if (tid == 0) blockSums[blockIdx.x] = sdata[0];
}

__global__ __launch_bounds__(1024) void scan_blocksums(
    int* __restrict__ blockSums, int NB)
{
    __shared__ int s[1024];
    int tid = threadIdx.x;
    int v = (tid < NB) ? blockSums[tid] : 0;
    s[tid] = v;
    __syncthreads();
    for (int off = 1; off < 1024; off <<= 1) {
        int t = (tid >= off) ? s[tid - off] : 0;
        __syncthreads();
        s[tid] += t;
        __syncthreads();
    }
    if (tid < NB) blockSums[tid] = s[tid] - v;   // exclusive
}

__global__ __launch_bounds__(256) void scan_final(
    const int* __restrict__ deg, const int* __restrict__ blockSums,
    int* __restrict__ offsets, int* __restrict__ cur, int N, int E)
{
    __shared__ int sdata[256];
    int base = blockIdx.x * 1024;
    int tid  = threadIdx.x;
    int loc[4];
    int s = 0;
    #pragma unroll
    for (int j = 0; j < 4; ++j) {
        int i = base + tid * 4 + j;
        loc[j] = (i < N) ? deg[i] : 0;
        s += loc[j];
    }
    int mine = s;
    sdata[tid] = s;
    __syncthreads();
    for (int off = 1; off < 256; off <<= 1) {
        int t = (tid >= off) ? sdata[tid - off] : 0;
        __syncthreads();
        sdata[tid] += t;
        __syncthreads();
    }
    int prefix = blockSums[blockIdx.x] + sdata[tid] - mine;
    #pragma unroll
    for (int j = 0; j < 4; ++j) {
        int i = base + tid * 4 + j;
        if (i < N) { offsets[i] = prefix; cur[i] = prefix; prefix += loc[j]; }
    }
    if (blockIdx.x == 0 && tid == 0) offsets[N] = E;
}

__global__ __launch_bounds__(256) void fill_kernel(
    const int* __restrict__ col, int* __restrict__ cur,
    int* __restrict__ eidx, int E)
{
    int e = blockIdx.x * 256 + threadIdx.x;
    if (e < E) {
        int p = atomicAdd(&cur[col[e]], 1);
        eidx[p] = e;
    }
}

// ---------- prep: W1,W2 (fp32 row-major) -> Wt (bf16, transposed [col][k]) ----------
__global__ __launch_bounds__(256) void prep_w(
    const float* __restrict__ W1, const float* __restrict__ W2,
    unsigned short* __restrict__ Wt1, unsigned short* __restrict__ Wt2)
{
    int id = blockIdx.x * 256 + threadIdx.x;
    if (id < HID * K1) {                     // Wt1: [128][320]
        int c = id / K1, k = id - c * K1;
        Wt1[id] = f2bf(W1[(size_t)k * HID + c]);
    }
    if (id < HID * HID) {                    // Wt2: [128][128]
        int c = id >> 7, k = id & 127;
        Wt2[id] = f2bf(W2[(size_t)k * HID + c]);
    }
}

// ---------- gather: agg[n] = sum of edge_attr rows (CSR), bf16 out ----------
__global__ __launch_bounds__(256) void gather_kernel(
    const float* __restrict__ edge_attr,
    const int*   __restrict__ offsets,
    const int*   __restrict__ eidx,
    unsigned short* __restrict__ aggb, int N)
{
    int gid = blockIdx.x * 256 + threadIdx.x;
    int n = gid >> 5;
    int c = gid & 31;
    if (n >= N) return;
    int s = offsets[n];
    int t = offsets[n + 1];
    float4 a0 = make_float4(0.f, 0.f, 0.f, 0.f);
    float4 a1 = make_float4(0.f, 0.f, 0.f, 0.f);
    int p = s;
    while (p + 1 < t) {                       // 2 edges in flight
        int e0 = eidx[p], e1 = eidx[p + 1];
        float4 v0 = ((const float4*)(edge_attr + (size_t)e0 * HID))[c];
        float4 v1 = ((const float4*)(edge_attr + (size_t)e1 * HID))[c];
        a0.x += v0.x; a0.y += v0.y; a0.z += v0.z; a0.w += v0.w;
        a1.x += v1.x; a1.y += v1.y; a1.z += v1.z; a1.w += v1.w;
        p += 2;
    }
    if (p < t) {
        int e0 = eidx[p];
        float4 v0 = ((const float4*)(edge_attr + (size_t)e0 * HID))[c];
        a0.x += v0.x; a0.y += v0.y; a0.z += v0.z; a0.w += v0.w;
    }
    ushort4 o;
    o.x = f2bf(a0.x + a1.x); o.y = f2bf(a0.y + a1.y);
    o.z = f2bf(a0.z + a1.z); o.w = f2bf(a0.w + a1.w);
    ((ushort4*)(aggb + (size_t)n * HID))[c] = o;
}

// ---------- fused 2-layer MLP via bf16 MFMA ----------
// block = 512 threads = 8 waves; wave w owns output cols [16w, 16w+15].
// 16 nodes per block (N = 100000 = 6250 * 16, no tail).
// A tile [16][328] bf16 (pad 320->328: 16B-aligned rows, 2-way bank alias = free),
// H tile [16][136] bf16. W fragments live in registers (identical for all blocks).
#define ROWS 16
#define LDA_E 328
#define LDH_E 136

__global__ __launch_bounds__(512, 4) void mlp_mfma(
    const float* __restrict__ x,
    const unsigned short* __restrict__ aggb,
    const float* __restrict__ u,
    const int*   __restrict__ batch,
    const unsigned short* __restrict__ Wt1,
    const unsigned short* __restrict__ Wt2,
    const float* __restrict__ b1, const float* __restrict__ b2,
    float* __restrict__ out, int N)
{
    __shared__ __align__(16) unsigned short A[ROWS * LDA_E];
    __shared__ __align__(16) unsigned short H[ROWS * LDH_E];
    const int tid  = threadIdx.x;
    const int n0   = blockIdx.x * ROWS;
    const int lane = tid & 63;
    const int wave = tid >> 6;       // 0..7 = which 16-col slice
    const int l15  = lane & 15;
    const int lhi  = lane >> 4;      // 0..3
    const int wcol = wave * 16 + l15;

    // ---- prologue: W fragments into registers (B-operand: col=l15, k contiguous)
    bf16x8 w1f[10], w2f[4];
    #pragma unroll
    for (int ks = 0; ks < 10; ++ks)
        w1f[ks] = *(const bf16x8*)(Wt1 + (size_t)wcol * K1 + ks * 32 + lhi * 8);
    #pragma unroll
    for (int ks = 0; ks < 4; ++ks)
        w2f[ks] = *(const bf16x8*)(Wt2 + (size_t)wcol * HID + ks * 32 + lhi * 8);
    const float b1v = b1[wcol];
    const float b2v = b2[wcol];

    // ---- stage A tile: 64 segs per row = 32 x-float4 + 16 agg-uint4 + 16 u-float4
    #pragma unroll
    for (int it = 0; it < 2; ++it) {                 // ROWS*64 = 1024 = 2*512
        int t   = tid + it * 512;
        int row = t >> 6;
        int s   = t & 63;
        int n   = n0 + row;
        unsigned short* Arow = &A[row * LDA_E];
        if (s < 32) {                                // x: cols 0..127
            float4 v = make_float4(0.f, 0.f, 0.f, 0.f);
            if (n < N) v = ((const float4*)(x + (size_t)n * V_IN))[s];
            ushort4 o; o.x = f2bf(v.x); o.y = f2bf(v.y); o.z = f2bf(v.z); o.w = f2bf(v.w);
            *(ushort4*)&Arow[s * 4] = o;
        } else if (s < 48) {                         // agg: cols 128..255 (16 x 8 bf16)
            uint4 v = make_uint4(0u, 0u, 0u, 0u);
            if (n < N) v = ((const uint4*)(aggb + (size_t)n * HID))[s - 32];
            *(uint4*)&Arow[V_IN + (s - 32) * 8] = v;
        } else {                                     // u: cols 256..319
            float4 v = make_float4(0.f, 0.f, 0.f, 0.f);
            if (n < N) {
                int b = batch[n];
                v = ((const float4*)(u + (size_t)b * U_IN))[s - 48];
            }
            ushort4 o; o.x = f2bf(v.x); o.y = f2bf(v.y); o.z = f2bf(v.z); o.w = f2bf(v.w);
            *(ushort4*)&Arow[V_IN + HID + (s - 48) * 4] = o;
        }
    }
    __syncthreads();

    // ---- layer 1: acc[16x16] = A[16x320] @ W1[320 x 16-slice]
    f32x4 acc = {0.f, 0.f, 0.f, 0.f};
    #pragma unroll
    for (int ks = 0; ks < 10; ++ks) {
        bf16x8 af = *(const bf16x8*)&A[l15 * LDA_E + ks * 32 + lhi * 8];
        acc = __builtin_amdgcn_mfma_f32_16x16x32_bf16(af, w1f[ks], acc, 0, 0, 0);
    }
    // bias + relu -> H (D layout: row = lhi*4+r, col = l15 in wave's slice)
    #pragma unroll
    for (int r = 0; r < 4; ++r) {
        float h = fmaxf(acc[r] + b1v, 0.f);
        H[(lhi * 4 + r) * LDH_E + wcol] = f2bf(h);
    }
    __syncthreads();

    // ---- layer 2: acc2[16x16] = H[16x128] @ W2[128 x 16-slice]
    f32x4 acc2 = {0.f, 0.f, 0.f, 0.f};
    #pragma unroll
    for (int ks = 0; ks < 4; ++ks) {
        bf16x8 hf = *(const bf16x8*)&H[l15 * LDH_E + ks * 32 + lhi * 8];
        acc2 = __builtin_amdgcn_mfma_f32_16x16x32_bf16(hf, w2f[ks], acc2, 0, 0, 0);
    }
    #pragma unroll
    for (int r = 0; r < 4; ++r) {
        int n = n0 + lhi * 4 + r;
        if (n < N) out[(size_t)n * HID + wcol] = acc2[r] + b2v;
    }
}

extern "C" void kernel_launch(void* const* d_in, const int* in_sizes, int n_in,
                              void* d_out, int out_size, void* d_ws, size_t ws_size,
                              hipStream_t stream) {
    const float* x          = (const float*)d_in[0];
    const int*   edge_index = (const int*)  d_in[1];
    const float* edge_attr  = (const float*)d_in[2];
    const float* u          = (const float*)d_in[3];
    const int*   batch      = (const int*)  d_in[4];
    const float* W1         = (const float*)d_in[5];
    const float* b1         = (const float*)d_in[6];
    const float* W2         = (const float*)d_in[7];
    const float* b2         = (const float*)d_in[8];
    float* out = (float*)d_out;

    const int N = in_sizes[0] / V_IN;
    const int E = in_sizes[1] / 2;
    const int* col = edge_index + E;   // row 1 = destination

    // ws layout
    unsigned short* aggb = (unsigned short*)d_ws;        // N*128 bf16
    unsigned short* Wt1  = aggb + (size_t)N * HID;       // 320*128
    unsigned short* Wt2  = Wt1 + (size_t)K1 * HID;       // 128*128
    int* deg       = (int*)(Wt2 + (size_t)HID * HID);
    int* cur       = deg + N;
    int* offsets   = cur + N;
    int* blockSums = offsets + N + 1;
    int* eidx      = blockSums + 2048;

    const int NB = (N + 1023) / 1024;

    hipMemsetAsync(deg, 0, (size_t)N * sizeof(int), stream);

    hist_kernel   <<<(E + 255) / 256, 256, 0, stream>>>(col, deg, E);
    scan_partial  <<<NB, 256, 0, stream>>>(deg, blockSums, N);
    scan_blocksums<<<1, 1024, 0, stream>>>(blockSums, NB);
    scan_final    <<<NB, 256, 0, stream>>>(deg, blockSums, offsets, cur, N, E);
    fill_kernel   <<<(E + 255) / 256, 256, 0, stream>>>(col, cur, eidx, E);
    prep_w        <<<(HID * K1 + 255) / 256, 256, 0, stream>>>(W1, W2, Wt1, Wt2);

    gather_kernel <<<((size_t)N * 32 + 255) / 256, 256, 0, stream>>>(
        edge_attr, offsets, eidx, aggb, N);

    mlp_mfma<<<(N + ROWS - 1) / ROWS, 512, 0, stream>>>(
        x, aggb, u, batch, Wt1, Wt2, b1, b2, out, N);
}

// Round 6
// 286.298 us; speedup vs baseline: 4.8931x; 1.0035x over previous
//
#include <hip/hip_runtime.h>

#define V_IN 128
#define U_IN 64
#define HID 128
#define K1  (V_IN + HID + U_IN)   // 320

typedef __attribute__((ext_vector_type(8))) short bf16x8;
typedef __attribute__((ext_vector_type(4))) float f32x4;

static __device__ __forceinline__ unsigned short f2bf(float f) {
    union { float f; unsigned u; } v; v.f = f;
    unsigned r = v.u + 0x7FFFu + ((v.u >> 16) & 1u);   // RNE
    return (unsigned short)(r >> 16);
}

// ---------- zero deg (replaces hipMemsetAsync: rocclr fill ran at 2.3 GB/s, 184 us) ----------
__global__ __launch_bounds__(256) void zero_kernel(int* __restrict__ p, int n)
{
    int i = blockIdx.x * 256 + threadIdx.x;
    if (i < n) p[i] = 0;
}

// ---------- CSR build ----------

__global__ __launch_bounds__(256) void hist_kernel(
    const int* __restrict__ col, int* __restrict__ deg, int E)
{
    int e = blockIdx.x * 256 + threadIdx.x;
    if (e < E) atomicAdd(&deg[col[e]], 1);
}

__global__ __launch_bounds__(256) void scan_partial(
    const int* __restrict__ deg, int* __restrict__ blockSums, int N)
{
    __shared__ int sdata[256];
    int base = blockIdx.x * 1024;
    int tid  = threadIdx.x;
    int s = 0;
    #pragma unroll
    for (int j = 0; j < 4; ++j) {
        int i = base + tid * 4 + j;
        if (i < N) s += deg[i];
    }
    sdata[tid] = s;
    __syncthreads();
    for (int off = 128; off > 0; off >>= 1) {
        if (tid < off) sdata[tid] += sdata[tid + off];
        __syncthreads();
    }
    if (tid == 0) blockSums[blockIdx.x] = sdata[0];
}

__global__ __launch_bounds__(1024) void scan_blocksums(
    int* __restrict__ blockSums, int NB)
{
    __shared__ int s[1024];
    int tid = threadIdx.x;
    int v = (tid < NB) ? blockSums[tid] : 0;
    s[tid] = v;
    __syncthreads();
    for (int off = 1; off < 1024; off <<= 1) {
        int t = (tid >= off) ? s[tid - off] : 0;
        __syncthreads();
        s[tid] += t;
        __syncthreads();
    }
    if (tid < NB) blockSums[tid] = s[tid] - v;   // exclusive
}

__global__ __launch_bounds__(256) void scan_final(
    const int* __restrict__ deg, const int* __restrict__ blockSums,
    int* __restrict__ offsets, int* __restrict__ cur, int N, int E)
{
    __shared__ int sdata[256];
    int base = blockIdx.x * 1024;
    int tid  = threadIdx.x;
    int loc[4];
    int s = 0;
    #pragma unroll
    for (int j = 0; j < 4; ++j) {
        int i = base + tid * 4 + j;
        loc[j] = (i < N) ? deg[i] : 0;
        s += loc[j];
    }
    int mine = s;
    sdata[tid] = s;
    __syncthreads();
    for (int off = 1; off < 256; off <<= 1) {
        int t = (tid >= off) ? sdata[tid - off] : 0;
        __syncthreads();
        sdata[tid] += t;
        __syncthreads();
    }
    int prefix = blockSums[blockIdx.x] + sdata[tid] - mine;
    #pragma unroll
    for (int j = 0; j < 4; ++j) {
        int i = base + tid * 4 + j;
        if (i < N) { offsets[i] = prefix; cur[i] = prefix; prefix += loc[j]; }
    }
    if (blockIdx.x == 0 && tid == 0) offsets[N] = E;
}

__global__ __launch_bounds__(256) void fill_kernel(
    const int* __restrict__ col, int* __restrict__ cur,
    int* __restrict__ eidx, int E)
{
    int e = blockIdx.x * 256 + threadIdx.x;
    if (e < E) {
        int p = atomicAdd(&cur[col[e]], 1);
        eidx[p] = e;
    }
}

// ---------- prep: W1,W2 (fp32 row-major) -> Wt (bf16, transposed [col][k]) ----------
__global__ __launch_bounds__(256) void prep_w(
    const float* __restrict__ W1, const float* __restrict__ W2,
    unsigned short* __restrict__ Wt1, unsigned short* __restrict__ Wt2)
{
    int id = blockIdx.x * 256 + threadIdx.x;
    if (id < HID * K1) {                     // Wt1: [128][320]
        int c = id / K1, k = id - c * K1;
        Wt1[id] = f2bf(W1[(size_t)k * HID + c]);
    }
    if (id < HID * HID) {                    // Wt2: [128][128]
        int c = id >> 7, k = id & 127;
        Wt2[id] = f2bf(W2[(size_t)k * HID + c]);
    }
}

// ---------- gather: agg[n] = sum of edge_attr rows (CSR), bf16 out ----------
__global__ __launch_bounds__(256) void gather_kernel(
    const float* __restrict__ edge_attr,
    const int*   __restrict__ offsets,
    const int*   __restrict__ eidx,
    unsigned short* __restrict__ aggb, int N)
{
    int gid = blockIdx.x * 256 + threadIdx.x;
    int n = gid >> 5;
    int c = gid & 31;
    if (n >= N) return;
    int s = offsets[n];
    int t = offsets[n + 1];
    float4 a0 = make_float4(0.f, 0.f, 0.f, 0.f);
    float4 a1 = make_float4(0.f, 0.f, 0.f, 0.f);
    int p = s;
    while (p + 1 < t) {                       // 2 edges in flight
        int e0 = eidx[p], e1 = eidx[p + 1];
        float4 v0 = ((const float4*)(edge_attr + (size_t)e0 * HID))[c];
        float4 v1 = ((const float4*)(edge_attr + (size_t)e1 * HID))[c];
        a0.x += v0.x; a0.y += v0.y; a0.z += v0.z; a0.w += v0.w;
        a1.x += v1.x; a1.y += v1.y; a1.z += v1.z; a1.w += v1.w;
        p += 2;
    }
    if (p < t) {
        int e0 = eidx[p];
        float4 v0 = ((const float4*)(edge_attr + (size_t)e0 * HID))[c];
        a0.x += v0.x; a0.y += v0.y; a0.z += v0.z; a0.w += v0.w;
    }
    ushort4 o;
    o.x = f2bf(a0.x + a1.x); o.y = f2bf(a0.y + a1.y);
    o.z = f2bf(a0.z + a1.z); o.w = f2bf(a0.w + a1.w);
    ((ushort4*)(aggb + (size_t)n * HID))[c] = o;
}

// ---------- fused 2-layer MLP via bf16 MFMA ----------
// block = 512 threads = 8 waves; wave w owns output cols [16w, 16w+15].
// 16 nodes per block (N = 100000 = 6250 * 16, no tail).
// A tile [16][328] bf16 (pad 320->328: 16B-aligned rows, 2-way bank alias = free),
// H tile [16][136] bf16. W fragments live in registers (identical for all blocks).
#define ROWS 16
#define LDA_E 328
#define LDH_E 136

__global__ __launch_bounds__(512, 4) void mlp_mfma(
    const float* __restrict__ x,
    const unsigned short* __restrict__ aggb,
    const float* __restrict__ u,
    const int*   __restrict__ batch,
    const unsigned short* __restrict__ Wt1,
    const unsigned short* __restrict__ Wt2,
    const float* __restrict__ b1, const float* __restrict__ b2,
    float* __restrict__ out, int N)
{
    __shared__ __align__(16) unsigned short A[ROWS * LDA_E];
    __shared__ __align__(16) unsigned short H[ROWS * LDH_E];
    const int tid  = threadIdx.x;
    const int n0   = blockIdx.x * ROWS;
    const int lane = tid & 63;
    const int wave = tid >> 6;       // 0..7 = which 16-col slice
    const int l15  = lane & 15;
    const int lhi  = lane >> 4;      // 0..3
    const int wcol = wave * 16 + l15;

    // ---- prologue: W fragments into registers (B-operand: col=l15, k contiguous)
    bf16x8 w1f[10], w2f[4];
    #pragma unroll
    for (int ks = 0; ks < 10; ++ks)
        w1f[ks] = *(const bf16x8*)(Wt1 + (size_t)wcol * K1 + ks * 32 + lhi * 8);
    #pragma unroll
    for (int ks = 0; ks < 4; ++ks)
        w2f[ks] = *(const bf16x8*)(Wt2 + (size_t)wcol * HID + ks * 32 + lhi * 8);
    const float b1v = b1[wcol];
    const float b2v = b2[wcol];

    // ---- stage A tile: 64 segs per row = 32 x-float4 + 16 agg-uint4 + 16 u-float4
    #pragma unroll
    for (int it = 0; it < 2; ++it) {                 // ROWS*64 = 1024 = 2*512
        int t   = tid + it * 512;
        int row = t >> 6;
        int s   = t & 63;
        int n   = n0 + row;
        unsigned short* Arow = &A[row * LDA_E];
        if (s < 32) {                                // x: cols 0..127
            float4 v = make_float4(0.f, 0.f, 0.f, 0.f);
            if (n < N) v = ((const float4*)(x + (size_t)n * V_IN))[s];
            ushort4 o; o.x = f2bf(v.x); o.y = f2bf(v.y); o.z = f2bf(v.z); o.w = f2bf(v.w);
            *(ushort4*)&Arow[s * 4] = o;
        } else if (s < 48) {                         // agg: cols 128..255 (16 x 8 bf16)
            uint4 v = make_uint4(0u, 0u, 0u, 0u);
            if (n < N) v = ((const uint4*)(aggb + (size_t)n * HID))[s - 32];
            *(uint4*)&Arow[V_IN + (s - 32) * 8] = v;
        } else {                                     // u: cols 256..319
            float4 v = make_float4(0.f, 0.f, 0.f, 0.f);
            if (n < N) {
                int b = batch[n];
                v = ((const float4*)(u + (size_t)b * U_IN))[s - 48];
            }
            ushort4 o; o.x = f2bf(v.x); o.y = f2bf(v.y); o.z = f2bf(v.z); o.w = f2bf(v.w);
            *(ushort4*)&Arow[V_IN + HID + (s - 48) * 4] = o;
        }
    }
    __syncthreads();

    // ---- layer 1: acc[16x16] = A[16x320] @ W1[320 x 16-slice]
    f32x4 acc = {0.f, 0.f, 0.f, 0.f};
    #pragma unroll
    for (int ks = 0; ks < 10; ++ks) {
        bf16x8 af = *(const bf16x8*)&A[l15 * LDA_E + ks * 32 + lhi * 8];
        acc = __builtin_amdgcn_mfma_f32_16x16x32_bf16(af, w1f[ks], acc, 0, 0, 0);
    }
    // bias + relu -> H (D layout: row = lhi*4+r, col = l15 in wave's slice)
    #pragma unroll
    for (int r = 0; r < 4; ++r) {
        float h = fmaxf(acc[r] + b1v, 0.f);
        H[(lhi * 4 + r) * LDH_E + wcol] = f2bf(h);
    }
    __syncthreads();

    // ---- layer 2: acc2[16x16] = H[16x128] @ W2[128 x 16-slice]
    f32x4 acc2 = {0.f, 0.f, 0.f, 0.f};
    #pragma unroll
    for (int ks = 0; ks < 4; ++ks) {
        bf16x8 hf = *(const bf16x8*)&H[l15 * LDH_E + ks * 32 + lhi * 8];
        acc2 = __builtin_amdgcn_mfma_f32_16x16x32_bf16(hf, w2f[ks], acc2, 0, 0, 0);
    }
    #pragma unroll
    for (int r = 0; r < 4; ++r) {
        int n = n0 + lhi * 4 + r;
        if (n < N) out[(size_t)n * HID + wcol] = acc2[r] + b2v;
    }
}

extern "C" void kernel_launch(void* const* d_in, const int* in_sizes, int n_in,
                              void* d_out, int out_size, void* d_ws, size_t ws_size,
                              hipStream_t stream) {
    const float* x          = (const float*)d_in[0];
    const int*   edge_index = (const int*)  d_in[1];
    const float* edge_attr  = (const float*)d_in[2];
    const float* u          = (const float*)d_in[3];
    const int*   batch      = (const int*)  d_in[4];
    const float* W1         = (const float*)d_in[5];
    const float* b1         = (const float*)d_in[6];
    const float* W2         = (const float*)d_in[7];
    const float* b2         = (const float*)d_in[8];
    float* out = (float*)d_out;

    const int N = in_sizes[0] / V_IN;
    const int E = in_sizes[1] / 2;
    const int* col = edge_index + E;   // row 1 = destination

    // ws layout
    unsigned short* aggb = (unsigned short*)d_ws;        // N*128 bf16
    unsigned short* Wt1  = aggb + (size_t)N * HID;       // 320*128
    unsigned short* Wt2  = Wt1 + (size_t)K1 * HID;       // 128*128
    int* deg       = (int*)(Wt2 + (size_t)HID * HID);
    int* cur       = deg + N;
    int* offsets   = cur + N;
    int* blockSums = offsets + N + 1;
    int* eidx      = blockSums + 2048;

    const int NB = (N + 1023) / 1024;

    zero_kernel   <<<(N + 255) / 256, 256, 0, stream>>>(deg, N);
    hist_kernel   <<<(E + 255) / 256, 256, 0, stream>>>(col, deg, E);
    scan_partial  <<<NB, 256, 0, stream>>>(deg, blockSums, N);
    scan_blocksums<<<1, 1024, 0, stream>>>(blockSums, NB);
    scan_final    <<<NB, 256, 0, stream>>>(deg, blockSums, offsets, cur, N, E);
    fill_kernel   <<<(E + 255) / 256, 256, 0, stream>>>(col, cur, eidx, E);
    prep_w        <<<(HID * K1 + 255) / 256, 256, 0, stream>>>(W1, W2, Wt1, Wt2);

    gather_kernel <<<((size_t)N * 32 + 255) / 256, 256, 0, stream>>>(
        edge_attr, offsets, eidx, aggb, N);

    mlp_mfma<<<(N + ROWS - 1) / ROWS, 512, 0, stream>>>(
        x, aggb, u, batch, Wt1, Wt2, b1, b2, out, N);
}

// Round 7
// 259.252 us; speedup vs baseline: 5.4036x; 1.1043x over previous
//
#include <hip/hip_runtime.h>

#define V_IN 128
#define U_IN 64
#define HID 128
#define K1  (V_IN + HID + U_IN)   // 320

typedef __attribute__((ext_vector_type(8))) short bf16x8;
typedef __attribute__((ext_vector_type(4))) float f32x4;

static __device__ __forceinline__ unsigned short f2bf(float f) {
    union { float f; unsigned u; } v; v.f = f;
    unsigned r = v.u + 0x7FFFu + ((v.u >> 16) & 1u);   // RNE
    return (unsigned short)(r >> 16);
}

// ---------- zero deg ----------
__global__ __launch_bounds__(256) void zero_kernel(int* __restrict__ p, int n)
{
    int i = blockIdx.x * 256 + threadIdx.x;
    if (i < n) p[i] = 0;
}

// ---------- CSR build ----------

__global__ __launch_bounds__(256) void hist_kernel(
    const int* __restrict__ col, int* __restrict__ deg, int E)
{
    int e = blockIdx.x * 256 + threadIdx.x;
    if (e < E) atomicAdd(&deg[col[e]], 1);
}

__global__ __launch_bounds__(256) void scan_partial(
    const int* __restrict__ deg, int* __restrict__ blockSums, int N)
{
    __shared__ int sdata[256];
    int base = blockIdx.x * 1024;
    int tid  = threadIdx.x;
    int s = 0;
    #pragma unroll
    for (int j = 0; j < 4; ++j) {
        int i = base + tid * 4 + j;
        if (i < N) s += deg[i];
    }
    sdata[tid] = s;
    __syncthreads();
    for (int off = 128; off > 0; off >>= 1) {
        if (tid < off) sdata[tid] += sdata[tid + off];
        __syncthreads();
    }
    if (tid == 0) blockSums[blockIdx.x] = sdata[0];
}

__global__ __launch_bounds__(1024) void scan_blocksums(
    int* __restrict__ blockSums, int NB)
{
    __shared__ int s[1024];
    int tid = threadIdx.x;
    int v = (tid < NB) ? blockSums[tid] : 0;
    s[tid] = v;
    __syncthreads();
    for (int off = 1; off < 1024; off <<= 1) {
        int t = (tid >= off) ? s[tid - off] : 0;
        __syncthreads();
        s[tid] += t;
        __syncthreads();
    }
    if (tid < NB) blockSums[tid] = s[tid] - v;   // exclusive
}

__global__ __launch_bounds__(256) void scan_final(
    const int* __restrict__ deg, const int* __restrict__ blockSums,
    int* __restrict__ offsets, int* __restrict__ cur, int N, int E)
{
    __shared__ int sdata[256];
    int base = blockIdx.x * 1024;
    int tid  = threadIdx.x;
    int loc[4];
    int s = 0;
    #pragma unroll
    for (int j = 0; j < 4; ++j) {
        int i = base + tid * 4 + j;
        loc[j] = (i < N) ? deg[i] : 0;
        s += loc[j];
    }
    int mine = s;
    sdata[tid] = s;
    __syncthreads();
    for (int off = 1; off < 256; off <<= 1) {
        int t = (tid >= off) ? sdata[tid - off] : 0;
        __syncthreads();
        sdata[tid] += t;
        __syncthreads();
    }
    int prefix = blockSums[blockIdx.x] + sdata[tid] - mine;
    #pragma unroll
    for (int j = 0; j < 4; ++j) {
        int i = base + tid * 4 + j;
        if (i < N) { offsets[i] = prefix; cur[i] = prefix; prefix += loc[j]; }
    }
    if (blockIdx.x == 0 && tid == 0) offsets[N] = E;
}

__global__ __launch_bounds__(256) void fill_kernel(
    const int* __restrict__ col, int* __restrict__ cur,
    int* __restrict__ eidx, int E)
{
    int e = blockIdx.x * 256 + threadIdx.x;
    if (e < E) {
        int p = atomicAdd(&cur[col[e]], 1);
        eidx[p] = e;
    }
}

// ---------- prep: W1,W2 (fp32 row-major) -> Wt (bf16, transposed [col][k]) ----------
__global__ __launch_bounds__(256) void prep_w(
    const float* __restrict__ W1, const float* __restrict__ W2,
    unsigned short* __restrict__ Wt1, unsigned short* __restrict__ Wt2)
{
    int id = blockIdx.x * 256 + threadIdx.x;
    if (id < HID * K1) {                     // Wt1: [128][320]
        int c = id / K1, k = id - c * K1;
        Wt1[id] = f2bf(W1[(size_t)k * HID + c]);
    }
    if (id < HID * HID) {                    // Wt2: [128][128]
        int c = id >> 7, k = id & 127;
        Wt2[id] = f2bf(W2[(size_t)k * HID + c]);
    }
}

// ---------- gather: agg[n] = sum of edge_attr rows (CSR), bf16 out, 4-deep ILP ----------
__global__ __launch_bounds__(256) void gather_kernel(
    const float* __restrict__ edge_attr,
    const int*   __restrict__ offsets,
    const int*   __restrict__ eidx,
    unsigned short* __restrict__ aggb, int N)
{
    int gid = blockIdx.x * 256 + threadIdx.x;
    int n = gid >> 5;
    int c = gid & 31;
    if (n >= N) return;
    int s = offsets[n];
    int t = offsets[n + 1];
    float4 a0 = make_float4(0.f, 0.f, 0.f, 0.f);
    float4 a1 = make_float4(0.f, 0.f, 0.f, 0.f);
    float4 a2 = make_float4(0.f, 0.f, 0.f, 0.f);
    float4 a3 = make_float4(0.f, 0.f, 0.f, 0.f);
    int p = s;
    while (p + 3 < t) {                       // 4 edges in flight
        int e0 = eidx[p], e1 = eidx[p + 1], e2 = eidx[p + 2], e3 = eidx[p + 3];
        float4 v0 = ((const float4*)(edge_attr + (size_t)e0 * HID))[c];
        float4 v1 = ((const float4*)(edge_attr + (size_t)e1 * HID))[c];
        float4 v2 = ((const float4*)(edge_attr + (size_t)e2 * HID))[c];
        float4 v3 = ((const float4*)(edge_attr + (size_t)e3 * HID))[c];
        a0.x += v0.x; a0.y += v0.y; a0.z += v0.z; a0.w += v0.w;
        a1.x += v1.x; a1.y += v1.y; a1.z += v1.z; a1.w += v1.w;
        a2.x += v2.x; a2.y += v2.y; a2.z += v2.z; a2.w += v2.w;
        a3.x += v3.x; a3.y += v3.y; a3.z += v3.z; a3.w += v3.w;
        p += 4;
    }
    while (p < t) {
        int e0 = eidx[p];
        float4 v0 = ((const float4*)(edge_attr + (size_t)e0 * HID))[c];
        a0.x += v0.x; a0.y += v0.y; a0.z += v0.z; a0.w += v0.w;
        ++p;
    }
    ushort4 o;
    o.x = f2bf((a0.x + a1.x) + (a2.x + a3.x));
    o.y = f2bf((a0.y + a1.y) + (a2.y + a3.y));
    o.z = f2bf((a0.z + a1.z) + (a2.z + a3.z));
    o.w = f2bf((a0.w + a1.w) + (a2.w + a3.w));
    ((ushort4*)(aggb + (size_t)n * HID))[c] = o;
}

// ---------- fused 2-layer MLP via bf16 MFMA ----------
// block = 512 threads = 8 waves; wave w owns output cols [16w, 16w+15].
// ROWS = 32 nodes per block: each wave computes TWO 16-row tiles with the SAME
// in-register W fragments (halves weight re-fetch and block count).
// A tile [32][328] bf16 (21 KB), H tile [32][136] bf16 (8.7 KB).
#define ROWS 32
#define LDA_E 328
#define LDH_E 136

__global__ __launch_bounds__(512, 4) void mlp_mfma(
    const float* __restrict__ x,
    const unsigned short* __restrict__ aggb,
    const float* __restrict__ u,
    const int*   __restrict__ batch,
    const unsigned short* __restrict__ Wt1,
    const unsigned short* __restrict__ Wt2,
    const float* __restrict__ b1, const float* __restrict__ b2,
    float* __restrict__ out, int N)
{
    __shared__ __align__(16) unsigned short A[ROWS * LDA_E];
    __shared__ __align__(16) unsigned short H[ROWS * LDH_E];
    const int tid  = threadIdx.x;
    const int n0   = blockIdx.x * ROWS;
    const int lane = tid & 63;
    const int wave = tid >> 6;       // 0..7 = which 16-col slice
    const int l15  = lane & 15;
    const int lhi  = lane >> 4;      // 0..3
    const int wcol = wave * 16 + l15;

    // ---- prologue: W fragments into registers (B-operand: col=l15, k contiguous)
    bf16x8 w1f[10], w2f[4];
    #pragma unroll
    for (int ks = 0; ks < 10; ++ks)
        w1f[ks] = *(const bf16x8*)(Wt1 + (size_t)wcol * K1 + ks * 32 + lhi * 8);
    #pragma unroll
    for (int ks = 0; ks < 4; ++ks)
        w2f[ks] = *(const bf16x8*)(Wt2 + (size_t)wcol * HID + ks * 32 + lhi * 8);
    const float b1v = b1[wcol];
    const float b2v = b2[wcol];

    // ---- stage A tile: 64 segs per row = 32 x-float4 + 16 agg-uint4 + 16 u-float4
    #pragma unroll
    for (int it = 0; it < 4; ++it) {                 // ROWS*64 = 2048 = 4*512
        int t   = tid + it * 512;
        int row = t >> 6;
        int s   = t & 63;
        int n   = n0 + row;
        unsigned short* Arow = &A[row * LDA_E];
        if (s < 32) {                                // x: cols 0..127
            float4 v = make_float4(0.f, 0.f, 0.f, 0.f);
            if (n < N) v = ((const float4*)(x + (size_t)n * V_IN))[s];
            ushort4 o; o.x = f2bf(v.x); o.y = f2bf(v.y); o.z = f2bf(v.z); o.w = f2bf(v.w);
            *(ushort4*)&Arow[s * 4] = o;
        } else if (s < 48) {                         // agg: cols 128..255 (16 x 8 bf16)
            uint4 v = make_uint4(0u, 0u, 0u, 0u);
            if (n < N) v = ((const uint4*)(aggb + (size_t)n * HID))[s - 32];
            *(uint4*)&Arow[V_IN + (s - 32) * 8] = v;
        } else {                                     // u: cols 256..319
            float4 v = make_float4(0.f, 0.f, 0.f, 0.f);
            if (n < N) {
                int b = batch[n];
                v = ((const float4*)(u + (size_t)b * U_IN))[s - 48];
            }
            ushort4 o; o.x = f2bf(v.x); o.y = f2bf(v.y); o.z = f2bf(v.z); o.w = f2bf(v.w);
            *(ushort4*)&Arow[V_IN + HID + (s - 48) * 4] = o;
        }
    }
    __syncthreads();

    // ---- layer 1: two 16-row tiles share w1f
    f32x4 acc[2] = {{0.f, 0.f, 0.f, 0.f}, {0.f, 0.f, 0.f, 0.f}};
    #pragma unroll
    for (int ks = 0; ks < 10; ++ks) {
        #pragma unroll
        for (int h = 0; h < 2; ++h) {
            bf16x8 af = *(const bf16x8*)&A[(h * 16 + l15) * LDA_E + ks * 32 + lhi * 8];
            acc[h] = __builtin_amdgcn_mfma_f32_16x16x32_bf16(af, w1f[ks], acc[h], 0, 0, 0);
        }
    }
    // bias + relu -> H (D layout: row = lhi*4+r, col = l15 in wave's slice)
    #pragma unroll
    for (int h = 0; h < 2; ++h)
        #pragma unroll
        for (int r = 0; r < 4; ++r) {
            float hv = fmaxf(acc[h][r] + b1v, 0.f);
            H[(h * 16 + lhi * 4 + r) * LDH_E + wcol] = f2bf(hv);
        }
    __syncthreads();

    // ---- layer 2: two 16-row tiles share w2f
    f32x4 acc2[2] = {{0.f, 0.f, 0.f, 0.f}, {0.f, 0.f, 0.f, 0.f}};
    #pragma unroll
    for (int ks = 0; ks < 4; ++ks) {
        #pragma unroll
        for (int h = 0; h < 2; ++h) {
            bf16x8 hf = *(const bf16x8*)&H[(h * 16 + l15) * LDH_E + ks * 32 + lhi * 8];
            acc2[h] = __builtin_amdgcn_mfma_f32_16x16x32_bf16(hf, w2f[ks], acc2[h], 0, 0, 0);
        }
    }
    #pragma unroll
    for (int h = 0; h < 2; ++h)
        #pragma unroll
        for (int r = 0; r < 4; ++r) {
            int n = n0 + h * 16 + lhi * 4 + r;
            if (n < N) out[(size_t)n * HID + wcol] = acc2[h][r] + b2v;
        }
}

extern "C" void kernel_launch(void* const* d_in, const int* in_sizes, int n_in,
                              void* d_out, int out_size, void* d_ws, size_t ws_size,
                              hipStream_t stream) {
    const float* x          = (const float*)d_in[0];
    const int*   edge_index = (const int*)  d_in[1];
    const float* edge_attr  = (const float*)d_in[2];
    const float* u          = (const float*)d_in[3];
    const int*   batch      = (const int*)  d_in[4];
    const float* W1         = (const float*)d_in[5];
    const float* b1         = (const float*)d_in[6];
    const float* W2         = (const float*)d_in[7];
    const float* b2         = (const float*)d_in[8];
    float* out = (float*)d_out;

    const int N = in_sizes[0] / V_IN;
    const int E = in_sizes[1] / 2;
    const int* col = edge_index + E;   // row 1 = destination

    // ws layout
    unsigned short* aggb = (unsigned short*)d_ws;        // N*128 bf16
    unsigned short* Wt1  = aggb + (size_t)N * HID;       // 320*128
    unsigned short* Wt2  = Wt1 + (size_t)K1 * HID;       // 128*128
    int* deg       = (int*)(Wt2 + (size_t)HID * HID);
    int* cur       = deg + N;
    int* offsets   = cur + N;
    int* blockSums = offsets + N + 1;
    int* eidx      = blockSums + 2048;

    const int NB = (N + 1023) / 1024;

    zero_kernel   <<<(N + 255) / 256, 256, 0, stream>>>(deg, N);
    hist_kernel   <<<(E + 255) / 256, 256, 0, stream>>>(col, deg, E);
    scan_partial  <<<NB, 256, 0, stream>>>(deg, blockSums, N);
    scan_blocksums<<<1, 1024, 0, stream>>>(blockSums, NB);
    scan_final    <<<NB, 256, 0, stream>>>(deg, blockSums, offsets, cur, N, E);
    fill_kernel   <<<(E + 255) / 256, 256, 0, stream>>>(col, cur, eidx, E);
    prep_w        <<<(HID * K1 + 255) / 256, 256, 0, stream>>>(W1, W2, Wt1, Wt2);

    gather_kernel <<<((size_t)N * 32 + 255) / 256, 256, 0, stream>>>(
        edge_attr, offsets, eidx, aggb, N);

    mlp_mfma<<<(N + ROWS - 1) / ROWS, 512, 0, stream>>>(
        x, aggb, u, batch, Wt1, Wt2, b1, b2, out, N);
}

// Round 8
// 230.603 us; speedup vs baseline: 6.0749x; 1.1242x over previous
//
#include <hip/hip_runtime.h>
#include <hip/hip_bf16.h>

#define V_IN 128
#define U_IN 64
#define HID 128
#define K1  (V_IN + HID + U_IN)   // 320

typedef __attribute__((ext_vector_type(8))) short bf16x8;
typedef __attribute__((ext_vector_type(4))) float f32x4;

static __device__ __forceinline__ unsigned short f2bf(float f) {
    __hip_bfloat16 h = __float2bfloat16(f);          // compiler emits v_cvt
    union { __hip_bfloat16 h; unsigned short u; } v; v.h = h;
    return v.u;
}
static __device__ __forceinline__ unsigned int f2bf2(float lo, float hi) {
    __hip_bfloat162 h2 = __float22bfloat162_rn(make_float2(lo, hi));  // v_cvt_pk_bf16_f32
    union { __hip_bfloat162 h; unsigned int u; } v; v.h = h2;
    return v.u;
}

// ---------- zero deg ----------
__global__ __launch_bounds__(256) void zero_kernel(int* __restrict__ p, int n)
{
    int i = blockIdx.x * 256 + threadIdx.x;
    if (i < n) p[i] = 0;
}

// ---------- CSR build ----------

__global__ __launch_bounds__(256) void hist_kernel(
    const int* __restrict__ col, int* __restrict__ deg, int E)
{
    int e = blockIdx.x * 256 + threadIdx.x;
    if (e < E) atomicAdd(&deg[col[e]], 1);
}

__global__ __launch_bounds__(256) void scan_partial(
    const int* __restrict__ deg, int* __restrict__ blockSums, int N)
{
    __shared__ int sdata[256];
    int base = blockIdx.x * 1024;
    int tid  = threadIdx.x;
    int s = 0;
    #pragma unroll
    for (int j = 0; j < 4; ++j) {
        int i = base + tid * 4 + j;
        if (i < N) s += deg[i];
    }
    sdata[tid] = s;
    __syncthreads();
    for (int off = 128; off > 0; off >>= 1) {
        if (tid < off) sdata[tid] += sdata[tid + off];
        __syncthreads();
    }
    if (tid == 0) blockSums[blockIdx.x] = sdata[0];
}

__global__ __launch_bounds__(1024) void scan_blocksums(
    int* __restrict__ blockSums, int NB)
{
    __shared__ int s[1024];
    int tid = threadIdx.x;
    int v = (tid < NB) ? blockSums[tid] : 0;
    s[tid] = v;
    __syncthreads();
    for (int off = 1; off < 1024; off <<= 1) {
        int t = (tid >= off) ? s[tid - off] : 0;
        __syncthreads();
        s[tid] += t;
        __syncthreads();
    }
    if (tid < NB) blockSums[tid] = s[tid] - v;   // exclusive
}

__global__ __launch_bounds__(256) void scan_final(
    const int* __restrict__ deg, const int* __restrict__ blockSums,
    int* __restrict__ offsets, int* __restrict__ cur, int N, int E)
{
    __shared__ int sdata[256];
    int base = blockIdx.x * 1024;
    int tid  = threadIdx.x;
    int loc[4];
    int s = 0;
    #pragma unroll
    for (int j = 0; j < 4; ++j) {
        int i = base + tid * 4 + j;
        loc[j] = (i < N) ? deg[i] : 0;
        s += loc[j];
    }
    int mine = s;
    sdata[tid] = s;
    __syncthreads();
    for (int off = 1; off < 256; off <<= 1) {
        int t = (tid >= off) ? sdata[tid - off] : 0;
        __syncthreads();
        sdata[tid] += t;
        __syncthreads();
    }
    int prefix = blockSums[blockIdx.x] + sdata[tid] - mine;
    #pragma unroll
    for (int j = 0; j < 4; ++j) {
        int i = base + tid * 4 + j;
        if (i < N) { offsets[i] = prefix; cur[i] = prefix; prefix += loc[j]; }
    }
    if (blockIdx.x == 0 && tid == 0) offsets[N] = E;
}

__global__ __launch_bounds__(256) void fill_kernel(
    const int* __restrict__ col, int* __restrict__ cur,
    int* __restrict__ eidx, int E)
{
    int e = blockIdx.x * 256 + threadIdx.x;
    if (e < E) {
        int p = atomicAdd(&cur[col[e]], 1);
        eidx[p] = e;
    }
}

// ---------- prep: W1,W2 (fp32 row-major) -> Wt (bf16, transposed [col][k]) ----------
__global__ __launch_bounds__(256) void prep_w(
    const float* __restrict__ W1, const float* __restrict__ W2,
    unsigned short* __restrict__ Wt1, unsigned short* __restrict__ Wt2)
{
    int id = blockIdx.x * 256 + threadIdx.x;
    if (id < HID * K1) {                     // Wt1: [128][320]
        int c = id / K1, k = id - c * K1;
        Wt1[id] = f2bf(W1[(size_t)k * HID + c]);
    }
    if (id < HID * HID) {                    // Wt2: [128][128]
        int c = id >> 7, k = id & 127;
        Wt2[id] = f2bf(W2[(size_t)k * HID + c]);
    }
}

// ---------- fused gather + 2-layer MLP via bf16 MFMA ----------
// block = 512 threads = 8 waves; wave w owns output cols [16w, 16w+15];
// ROWS = 32 nodes/block, each wave computes two 16-row tiles sharing its W frags.
// Staging: x/u segs (1536 tasks) + CSR gather of agg (1024 tasks, ILP-4 walks)
// all before one barrier -> agg never round-trips HBM.
#define ROWS 32
#define LDA_E 328
#define LDH_E 136

__global__ __launch_bounds__(512, 4) void mlp_mfma(
    const float* __restrict__ x,
    const float* __restrict__ edge_attr,
    const int*   __restrict__ offsets,
    const int*   __restrict__ eidx,
    const float* __restrict__ u,
    const int*   __restrict__ batch,
    const unsigned short* __restrict__ Wt1,
    const unsigned short* __restrict__ Wt2,
    const float* __restrict__ b1, const float* __restrict__ b2,
    float* __restrict__ out, int N)
{
    __shared__ __align__(16) unsigned short A[ROWS * LDA_E];
    __shared__ __align__(16) unsigned short H[ROWS * LDH_E];
    const int tid  = threadIdx.x;
    const int n0   = blockIdx.x * ROWS;
    const int lane = tid & 63;
    const int wave = tid >> 6;       // 0..7 = which 16-col slice
    const int l15  = lane & 15;
    const int lhi  = lane >> 4;      // 0..3
    const int wcol = wave * 16 + l15;

    // ---- stage x (32 float4 segs/row) and u (16 segs/row): 32*48 = 1536 tasks
    #pragma unroll
    for (int it = 0; it < 3; ++it) {
        int t   = tid + it * 512;
        int row = t / 48;
        int s   = t - row * 48;
        int n   = n0 + row;
        unsigned short* Arow = &A[row * LDA_E];
        float4 v = make_float4(0.f, 0.f, 0.f, 0.f);
        int colbase;
        if (s < 32) {                                // x: cols 0..127
            if (n < N) v = ((const float4*)(x + (size_t)n * V_IN))[s];
            colbase = s * 4;
        } else {                                     // u: cols 256..319
            if (n < N) {
                int b = batch[n];
                v = ((const float4*)(u + (size_t)b * U_IN))[s - 32];
            }
            colbase = V_IN + HID + (s - 32) * 4;
        }
        uint2 o; o.x = f2bf2(v.x, v.y); o.y = f2bf2(v.z, v.w);
        *(uint2*)&Arow[colbase] = o;
    }

    // ---- gather agg directly into A cols 128..255: 32 rows x 32 chunks = 1024 tasks
    #pragma unroll
    for (int it = 0; it < 2; ++it) {
        int t   = tid + it * 512;
        int row = t >> 5;
        int c   = t & 31;
        int n   = n0 + row;
        float4 a0 = make_float4(0.f, 0.f, 0.f, 0.f);
        float4 a1 = make_float4(0.f, 0.f, 0.f, 0.f);
        float4 a2 = make_float4(0.f, 0.f, 0.f, 0.f);
        float4 a3 = make_float4(0.f, 0.f, 0.f, 0.f);
        if (n < N) {
            int s  = offsets[n];
            int t2 = offsets[n + 1];
            int p  = s;
            while (p + 3 < t2) {                     // 4 edges in flight
                int e0 = eidx[p], e1 = eidx[p + 1], e2 = eidx[p + 2], e3 = eidx[p + 3];
                float4 v0 = ((const float4*)(edge_attr + (size_t)e0 * HID))[c];
                float4 v1 = ((const float4*)(edge_attr + (size_t)e1 * HID))[c];
                float4 v2 = ((const float4*)(edge_attr + (size_t)e2 * HID))[c];
                float4 v3 = ((const float4*)(edge_attr + (size_t)e3 * HID))[c];
                a0.x += v0.x; a0.y += v0.y; a0.z += v0.z; a0.w += v0.w;
                a1.x += v1.x; a1.y += v1.y; a1.z += v1.z; a1.w += v1.w;
                a2.x += v2.x; a2.y += v2.y; a2.z += v2.z; a2.w += v2.w;
                a3.x += v3.x; a3.y += v3.y; a3.z += v3.z; a3.w += v3.w;
                p += 4;
            }
            while (p < t2) {
                int e0 = eidx[p];
                float4 v0 = ((const float4*)(edge_attr + (size_t)e0 * HID))[c];
                a0.x += v0.x; a0.y += v0.y; a0.z += v0.z; a0.w += v0.w;
                ++p;
            }
        }
        uint2 o;
        o.x = f2bf2((a0.x + a1.x) + (a2.x + a3.x), (a0.y + a1.y) + (a2.y + a3.y));
        o.y = f2bf2((a0.z + a1.z) + (a2.z + a3.z), (a0.w + a1.w) + (a2.w + a3.w));
        *(uint2*)&A[row * LDA_E + V_IN + c * 4] = o;
    }

    // ---- W fragments into registers (B-operand: col=l15, k contiguous)
    bf16x8 w1f[10], w2f[4];
    #pragma unroll
    for (int ks = 0; ks < 10; ++ks)
        w1f[ks] = *(const bf16x8*)(Wt1 + (size_t)wcol * K1 + ks * 32 + lhi * 8);
    #pragma unroll
    for (int ks = 0; ks < 4; ++ks)
        w2f[ks] = *(const bf16x8*)(Wt2 + (size_t)wcol * HID + ks * 32 + lhi * 8);
    const float b1v = b1[wcol];
    const float b2v = b2[wcol];

    __syncthreads();

    // ---- layer 1: two 16-row tiles share w1f
    f32x4 acc[2] = {{0.f, 0.f, 0.f, 0.f}, {0.f, 0.f, 0.f, 0.f}};
    #pragma unroll
    for (int ks = 0; ks < 10; ++ks) {
        #pragma unroll
        for (int h = 0; h < 2; ++h) {
            bf16x8 af = *(const bf16x8*)&A[(h * 16 + l15) * LDA_E + ks * 32 + lhi * 8];
            acc[h] = __builtin_amdgcn_mfma_f32_16x16x32_bf16(af, w1f[ks], acc[h], 0, 0, 0);
        }
    }
    // bias + relu -> H (D layout: row = lhi*4+r, col = l15 in wave's slice)
    #pragma unroll
    for (int h = 0; h < 2; ++h)
        #pragma unroll
        for (int r = 0; r < 4; ++r) {
            float hv = fmaxf(acc[h][r] + b1v, 0.f);
            H[(h * 16 + lhi * 4 + r) * LDH_E + wcol] = f2bf(hv);
        }
    __syncthreads();

    // ---- layer 2: two 16-row tiles share w2f
    f32x4 acc2[2] = {{0.f, 0.f, 0.f, 0.f}, {0.f, 0.f, 0.f, 0.f}};
    #pragma unroll
    for (int ks = 0; ks < 4; ++ks) {
        #pragma unroll
        for (int h = 0; h < 2; ++h) {
            bf16x8 hf = *(const bf16x8*)&H[(h * 16 + l15) * LDH_E + ks * 32 + lhi * 8];
            acc2[h] = __builtin_amdgcn_mfma_f32_16x16x32_bf16(hf, w2f[ks], acc2[h], 0, 0, 0);
        }
    }
    #pragma unroll
    for (int h = 0; h < 2; ++h)
        #pragma unroll
        for (int r = 0; r < 4; ++r) {
            int n = n0 + h * 16 + lhi * 4 + r;
            if (n < N) out[(size_t)n * HID + wcol] = acc2[h][r] + b2v;
        }
}

extern "C" void kernel_launch(void* const* d_in, const int* in_sizes, int n_in,
                              void* d_out, int out_size, void* d_ws, size_t ws_size,
                              hipStream_t stream) {
    const float* x          = (const float*)d_in[0];
    const int*   edge_index = (const int*)  d_in[1];
    const float* edge_attr  = (const float*)d_in[2];
    const float* u          = (const float*)d_in[3];
    const int*   batch      = (const int*)  d_in[4];
    const float* W1         = (const float*)d_in[5];
    const float* b1         = (const float*)d_in[6];
    const float* W2         = (const float*)d_in[7];
    const float* b2         = (const float*)d_in[8];
    float* out = (float*)d_out;

    const int N = in_sizes[0] / V_IN;
    const int E = in_sizes[1] / 2;
    const int* col = edge_index + E;   // row 1 = destination

    // ws layout
    unsigned short* Wt1  = (unsigned short*)d_ws;        // 320*128 bf16
    unsigned short* Wt2  = Wt1 + (size_t)K1 * HID;       // 128*128 bf16
    int* deg       = (int*)(Wt2 + (size_t)HID * HID);
    int* cur       = deg + N;
    int* offsets   = cur + N;
    int* blockSums = offsets + N + 1;
    int* eidx      = blockSums + 2048;

    const int NB = (N + 1023) / 1024;

    zero_kernel   <<<(N + 255) / 256, 256, 0, stream>>>(deg, N);
    hist_kernel   <<<(E + 255) / 256, 256, 0, stream>>>(col, deg, E);
    scan_partial  <<<NB, 256, 0, stream>>>(deg, blockSums, N);
    scan_blocksums<<<1, 1024, 0, stream>>>(blockSums, NB);
    scan_final    <<<NB, 256, 0, stream>>>(deg, blockSums, offsets, cur, N, E);
    fill_kernel   <<<(E + 255) / 256, 256, 0, stream>>>(col, cur, eidx, E);
    prep_w        <<<(HID * K1 + 255) / 256, 256, 0, stream>>>(W1, W2, Wt1, Wt2);

    mlp_mfma<<<(N + ROWS - 1) / ROWS, 512, 0, stream>>>(
        x, edge_attr, offsets, eidx, u, batch, Wt1, Wt2, b1, b2, out, N);
}

// Round 9
// 207.735 us; speedup vs baseline: 6.7436x; 1.1101x over previous
//
#include <hip/hip_runtime.h>
#include <hip/hip_bf16.h>

#define V_IN 128
#define U_IN 64
#define HID 128
#define K1  (V_IN + HID + U_IN)   // 320

typedef __attribute__((ext_vector_type(8))) short bf16x8;
typedef __attribute__((ext_vector_type(4))) float f32x4;

static __device__ __forceinline__ unsigned short f2bf(float f) {
    __hip_bfloat16 h = __float2bfloat16(f);
    union { __hip_bfloat16 h; unsigned short u; } v; v.h = h;
    return v.u;
}
static __device__ __forceinline__ unsigned int f2bf2(float lo, float hi) {
    __hip_bfloat162 h2 = __float22bfloat162_rn(make_float2(lo, hi));  // v_cvt_pk_bf16_f32
    union { __hip_bfloat162 h; unsigned int u; } v; v.h = h2;
    return v.u;
}

// ---------- zero deg ----------
__global__ __launch_bounds__(256) void zero_kernel(int* __restrict__ p, int n)
{
    int i = blockIdx.x * 256 + threadIdx.x;
    if (i < n) p[i] = 0;
}

// ---------- CSR build ----------

__global__ __launch_bounds__(256) void hist_kernel(
    const int* __restrict__ col, int* __restrict__ deg, int E)
{
    int e = blockIdx.x * 256 + threadIdx.x;
    if (e < E) atomicAdd(&deg[col[e]], 1);
}

__global__ __launch_bounds__(256) void scan_partial(
    const int* __restrict__ deg, int* __restrict__ blockSums, int N)
{
    __shared__ int sdata[256];
    int base = blockIdx.x * 1024;
    int tid  = threadIdx.x;
    int s = 0;
    #pragma unroll
    for (int j = 0; j < 4; ++j) {
        int i = base + tid * 4 + j;
        if (i < N) s += deg[i];
    }
    sdata[tid] = s;
    __syncthreads();
    for (int off = 128; off > 0; off >>= 1) {
        if (tid < off) sdata[tid] += sdata[tid + off];
        __syncthreads();
    }
    if (tid == 0) blockSums[blockIdx.x] = sdata[0];
}

__global__ __launch_bounds__(1024) void scan_blocksums(
    int* __restrict__ blockSums, int NB)
{
    __shared__ int s[1024];
    int tid = threadIdx.x;
    int v = (tid < NB) ? blockSums[tid] : 0;
    s[tid] = v;
    __syncthreads();
    for (int off = 1; off < 1024; off <<= 1) {
        int t = (tid >= off) ? s[tid - off] : 0;
        __syncthreads();
        s[tid] += t;
        __syncthreads();
    }
    if (tid < NB) blockSums[tid] = s[tid] - v;   // exclusive
}

__global__ __launch_bounds__(256) void scan_final(
    const int* __restrict__ deg, const int* __restrict__ blockSums,
    int* __restrict__ offsets, int* __restrict__ cur, int N, int E)
{
    __shared__ int sdata[256];
    int base = blockIdx.x * 1024;
    int tid  = threadIdx.x;
    int loc[4];
    int s = 0;
    #pragma unroll
    for (int j = 0; j < 4; ++j) {
        int i = base + tid * 4 + j;
        loc[j] = (i < N) ? deg[i] : 0;
        s += loc[j];
    }
    int mine = s;
    sdata[tid] = s;
    __syncthreads();
    for (int off = 1; off < 256; off <<= 1) {
        int t = (tid >= off) ? sdata[tid - off] : 0;
        __syncthreads();
        sdata[tid] += t;
        __syncthreads();
    }
    int prefix = blockSums[blockIdx.x] + sdata[tid] - mine;
    #pragma unroll
    for (int j = 0; j < 4; ++j) {
        int i = base + tid * 4 + j;
        if (i < N) { offsets[i] = prefix; cur[i] = prefix; prefix += loc[j]; }
    }
    if (blockIdx.x == 0 && tid == 0) offsets[N] = E;
}

__global__ __launch_bounds__(256) void fill_kernel(
    const int* __restrict__ col, int* __restrict__ cur,
    int* __restrict__ eidx, int E)
{
    int e = blockIdx.x * 256 + threadIdx.x;
    if (e < E) {
        int p = atomicAdd(&cur[col[e]], 1);
        eidx[p] = e;
    }
}

// ---------- prep: W1,W2 (fp32 row-major) -> Wt (bf16, transposed [col][k]) ----------
__global__ __launch_bounds__(256) void prep_w(
    const float* __restrict__ W1, const float* __restrict__ W2,
    unsigned short* __restrict__ Wt1, unsigned short* __restrict__ Wt2)
{
    int id = blockIdx.x * 256 + threadIdx.x;
    if (id < HID * K1) {                     // Wt1: [128][320]
        int c = id / K1, k = id - c * K1;
        Wt1[id] = f2bf(W1[(size_t)k * HID + c]);
    }
    if (id < HID * HID) {                    // Wt2: [128][128]
        int c = id >> 7, k = id & 127;
        Wt2[id] = f2bf(W2[(size_t)k * HID + c]);
    }
}

// ---------- fused gather + 2-layer MLP via bf16 MFMA ----------
// block = 512 threads = 8 waves; wave w owns output cols [16w, 16w+15];
// ROWS = 32 nodes/block, two 16-row tiles per wave share its in-reg W frags.
// NEW (R9): per-tile eidx slice staged in LDS (removes dependent global eidx
// load from the gather address chain); edge_attr via nontemporal loads
// (read-once data, don't thrash L2).
#define ROWS 32
#define LDA_E 328
#define LDH_E 136
#define ECAP 1280

__global__ __launch_bounds__(512, 4) void mlp_mfma(
    const float* __restrict__ x,
    const float* __restrict__ edge_attr,
    const int*   __restrict__ offsets,
    const int*   __restrict__ eidx,
    const float* __restrict__ u,
    const int*   __restrict__ batch,
    const unsigned short* __restrict__ Wt1,
    const unsigned short* __restrict__ Wt2,
    const float* __restrict__ b1, const float* __restrict__ b2,
    float* __restrict__ out, int N)
{
    __shared__ __align__(16) unsigned short A[ROWS * LDA_E];
    __shared__ __align__(16) unsigned short H[ROWS * LDH_E];
    __shared__ int Eidx[ECAP];
    const int tid  = threadIdx.x;
    const int n0   = blockIdx.x * ROWS;
    const int lane = tid & 63;
    const int wave = tid >> 6;       // 0..7 = which 16-col slice
    const int l15  = lane & 15;
    const int lhi  = lane >> 4;      // 0..3
    const int wcol = wave * 16 + l15;

    // ---- stage this tile's eidx slice into LDS (coalesced, once)
    const int nEnd   = (n0 + ROWS < N) ? n0 + ROWS : N;
    const int s_base = offsets[n0];
    const int s_end  = offsets[nEnd];
    const int cnt    = (s_end - s_base < ECAP) ? s_end - s_base : ECAP;
    for (int i = tid; i < cnt; i += 512) Eidx[i] = eidx[s_base + i];

    // ---- stage x (32 float4 segs/row) and u (16 segs/row): 32*48 = 1536 tasks
    #pragma unroll
    for (int it = 0; it < 3; ++it) {
        int t   = tid + it * 512;
        int row = t / 48;
        int s   = t - row * 48;
        int n   = n0 + row;
        unsigned short* Arow = &A[row * LDA_E];
        float4 v = make_float4(0.f, 0.f, 0.f, 0.f);
        int colbase;
        if (s < 32) {                                // x: cols 0..127
            if (n < N) v = ((const float4*)(x + (size_t)n * V_IN))[s];
            colbase = s * 4;
        } else {                                     // u: cols 256..319
            if (n < N) {
                int b = batch[n];
                v = ((const float4*)(u + (size_t)b * U_IN))[s - 32];
            }
            colbase = V_IN + HID + (s - 32) * 4;
        }
        uint2 o; o.x = f2bf2(v.x, v.y); o.y = f2bf2(v.z, v.w);
        *(uint2*)&Arow[colbase] = o;
    }
    __syncthreads();   // Eidx visible

    // ---- gather agg into A cols 128..255: 32 rows x 32 chunks, ILP-4,
    //      indices from LDS, rows via nontemporal loads
    #pragma unroll
    for (int it = 0; it < 2; ++it) {
        int t   = tid + it * 512;
        int row = t >> 5;
        int c   = t & 31;
        int n   = n0 + row;
        f32x4 a0 = {0.f, 0.f, 0.f, 0.f};
        f32x4 a1 = {0.f, 0.f, 0.f, 0.f};
        f32x4 a2 = {0.f, 0.f, 0.f, 0.f};
        f32x4 a3 = {0.f, 0.f, 0.f, 0.f};
        if (n < N) {
            int ls = offsets[n]     - s_base;
            int le = offsets[n + 1] - s_base;
            int j = ls;
            for (; j + 3 < le; j += 4) {
                int e0, e1, e2, e3;
                if (j + 3 < ECAP) {
                    e0 = Eidx[j];     e1 = Eidx[j + 1];
                    e2 = Eidx[j + 2]; e3 = Eidx[j + 3];
                } else {
                    e0 = eidx[s_base + j];     e1 = eidx[s_base + j + 1];
                    e2 = eidx[s_base + j + 2]; e3 = eidx[s_base + j + 3];
                }
                f32x4 v0 = __builtin_nontemporal_load((const f32x4*)(edge_attr + (size_t)e0 * HID) + c);
                f32x4 v1 = __builtin_nontemporal_load((const f32x4*)(edge_attr + (size_t)e1 * HID) + c);
                f32x4 v2 = __builtin_nontemporal_load((const f32x4*)(edge_attr + (size_t)e2 * HID) + c);
                f32x4 v3 = __builtin_nontemporal_load((const f32x4*)(edge_attr + (size_t)e3 * HID) + c);
                a0 += v0; a1 += v1; a2 += v2; a3 += v3;
            }
            for (; j < le; ++j) {
                int e0 = (j < ECAP) ? Eidx[j] : eidx[s_base + j];
                a0 += __builtin_nontemporal_load((const f32x4*)(edge_attr + (size_t)e0 * HID) + c);
            }
        }
        f32x4 asum = (a0 + a1) + (a2 + a3);
        uint2 o;
        o.x = f2bf2(asum[0], asum[1]);
        o.y = f2bf2(asum[2], asum[3]);
        *(uint2*)&A[row * LDA_E + V_IN + c * 4] = o;
    }

    // ---- W fragments into registers (B-operand: col=l15, k contiguous)
    bf16x8 w1f[10], w2f[4];
    #pragma unroll
    for (int ks = 0; ks < 10; ++ks)
        w1f[ks] = *(const bf16x8*)(Wt1 + (size_t)wcol * K1 + ks * 32 + lhi * 8);
    #pragma unroll
    for (int ks = 0; ks < 4; ++ks)
        w2f[ks] = *(const bf16x8*)(Wt2 + (size_t)wcol * HID + ks * 32 + lhi * 8);
    const float b1v = b1[wcol];
    const float b2v = b2[wcol];

    __syncthreads();

    // ---- layer 1: two 16-row tiles share w1f
    f32x4 acc[2] = {{0.f, 0.f, 0.f, 0.f}, {0.f, 0.f, 0.f, 0.f}};
    #pragma unroll
    for (int ks = 0; ks < 10; ++ks) {
        #pragma unroll
        for (int h = 0; h < 2; ++h) {
            bf16x8 af = *(const bf16x8*)&A[(h * 16 + l15) * LDA_E + ks * 32 + lhi * 8];
            acc[h] = __builtin_amdgcn_mfma_f32_16x16x32_bf16(af, w1f[ks], acc[h], 0, 0, 0);
        }
    }
    // bias + relu -> H (D layout: row = lhi*4+r, col = l15 in wave's slice)
    #pragma unroll
    for (int h = 0; h < 2; ++h)
        #pragma unroll
        for (int r = 0; r < 4; ++r) {
            float hv = fmaxf(acc[h][r] + b1v, 0.f);
            H[(h * 16 + lhi * 4 + r) * LDH_E + wcol] = f2bf(hv);
        }
    __syncthreads();

    // ---- layer 2: two 16-row tiles share w2f
    f32x4 acc2[2] = {{0.f, 0.f, 0.f, 0.f}, {0.f, 0.f, 0.f, 0.f}};
    #pragma unroll
    for (int ks = 0; ks < 4; ++ks) {
        #pragma unroll
        for (int h = 0; h < 2; ++h) {
            bf16x8 hf = *(const bf16x8*)&H[(h * 16 + l15) * LDH_E + ks * 32 + lhi * 8];
            acc2[h] = __builtin_amdgcn_mfma_f32_16x16x32_bf16(hf, w2f[ks], acc2[h], 0, 0, 0);
        }
    }
    #pragma unroll
    for (int h = 0; h < 2; ++h)
        #pragma unroll
        for (int r = 0; r < 4; ++r) {
            int n = n0 + h * 16 + lhi * 4 + r;
            if (n < N) out[(size_t)n * HID + wcol] = acc2[h][r] + b2v;
        }
}

extern "C" void kernel_launch(void* const* d_in, const int* in_sizes, int n_in,
                              void* d_out, int out_size, void* d_ws, size_t ws_size,
                              hipStream_t stream) {
    const float* x          = (const float*)d_in[0];
    const int*   edge_index = (const int*)  d_in[1];
    const float* edge_attr  = (const float*)d_in[2];
    const float* u          = (const float*)d_in[3];
    const int*   batch      = (const int*)  d_in[4];
    const float* W1         = (const float*)d_in[5];
    const float* b1         = (const float*)d_in[6];
    const float* W2         = (const float*)d_in[7];
    const float* b2         = (const float*)d_in[8];
    float* out = (float*)d_out;

    const int N = in_sizes[0] / V_IN;
    const int E = in_sizes[1] / 2;
    const int* col = edge_index + E;   // row 1 = destination

    // ws layout
    unsigned short* Wt1  = (unsigned short*)d_ws;        // 320*128 bf16
    unsigned short* Wt2  = Wt1 + (size_t)K1 * HID;       // 128*128 bf16
    int* deg       = (int*)(Wt2 + (size_t)HID * HID);
    int* cur       = deg + N;
    int* offsets   = cur + N;
    int* blockSums = offsets + N + 1;
    int* eidx      = blockSums + 2048;

    const int NB = (N + 1023) / 1024;

    zero_kernel   <<<(N + 255) / 256, 256, 0, stream>>>(deg, N);
    hist_kernel   <<<(E + 255) / 256, 256, 0, stream>>>(col, deg, E);
    scan_partial  <<<NB, 256, 0, stream>>>(deg, blockSums, N);
    scan_blocksums<<<1, 1024, 0, stream>>>(blockSums, NB);
    scan_final    <<<NB, 256, 0, stream>>>(deg, blockSums, offsets, cur, N, E);
    fill_kernel   <<<(E + 255) / 256, 256, 0, stream>>>(col, cur, eidx, E);
    prep_w        <<<(HID * K1 + 255) / 256, 256, 0, stream>>>(W1, W2, Wt1, Wt2);

    mlp_mfma<<<(N + ROWS - 1) / ROWS, 512, 0, stream>>>(
        x, edge_attr, offsets, eidx, u, batch, Wt1, Wt2, b1, b2, out, N);
}